// Round 2
// baseline (903.165 us; speedup 1.0000x reference)
//
#include <hip/hip_runtime.h>
#include <math.h>

// ---------------------------------------------------------------------------
// RiemannianPooling: logm(eigh) -> mean -> diff_exp -> cov -> cholesky -> bimap
// N=32, M*T*V=3200, C=16, D=136, out 32x64x64 fp32.
// R9: (1) all-DPP shuffles — non-native XOR masks done as 2-DPP compositions
//     (4=3^7, 5=2^7, 6=1^7, 9=1^8, 10=2^8, 11=3^8, 12=3^15, 13=2^15, 14=1^15),
//     removing ds_swizzle + lgkmcnt stalls from the Jacobi hot loop entirely.
//     (2) k_chol split — Cholesky kernel (32 blocks) now ends at the factor +
//     trace; Tout and bimap move to k_tout/k_bimap at 256 blocks each (8x
//     parallelism for the matmul phases, float4 LDS dots in bimap).
//     Numerically identical accumulation order. Rest frozen from R8.
// ---------------------------------------------------------------------------

#define EPSV 1e-4f
#define NSWEEP_BIG 6
#define NSWEEP_SMALL 10
#define SQRT2F 1.41421356237309515f

// workspace layout (float offsets) — total 66.5 MB
#define OFF_G      0            // 136
#define OFF_WBT    160          // 137*64 = 8768
#define OFF_MEAN   8960         // 32*136
#define OFF_XM     13312        // 32*136
#define OFF_TR     17664        // 32*2 (tr, 1/tr)
#define OFF_CT     17792        // 32*9320 tri-packed cholesky factor (ends 316032)
#define OFF_MPART  320000       // 6400*136 (aliases head of PART)
#define OFF_PART   320000       // 8*32*9316 (written after MPART consumed)
#define OFF_TT     320000       // 32*8960 Tout^T (aliases PART, dead after k_chol)
#define OFF_L      2704896      // 102400*136

typedef float v2f __attribute__((ext_vector_type(2)));

__device__ __forceinline__ float rcp_f(float x){ return __builtin_amdgcn_rcpf(x); }
__device__ __forceinline__ float rsq_f(float x){ return __builtin_amdgcn_rsqf(x); }

// XOR within 16-lane rows via single DPP (VALU pipe). Native masks:
// 1,2,3 (quad_perm), 7 (row_half_mirror), 8 (row_ror:8), 15 (row_mirror).
template<int R>
__device__ __forceinline__ float xl(float x){
    int s = __float_as_int(x);
    if constexpr (R == 1){
        return __int_as_float(__builtin_amdgcn_update_dpp(s, s, 0xB1, 0xF, 0xF, false));
    } else if constexpr (R == 2){
        return __int_as_float(__builtin_amdgcn_update_dpp(s, s, 0x4E, 0xF, 0xF, false));
    } else if constexpr (R == 3){
        return __int_as_float(__builtin_amdgcn_update_dpp(s, s, 0x1B, 0xF, 0xF, false));
    } else if constexpr (R == 7){
        return __int_as_float(__builtin_amdgcn_update_dpp(s, s, 0x141, 0xF, 0xF, false));
    } else if constexpr (R == 8){
        return __int_as_float(__builtin_amdgcn_update_dpp(s, s, 0x128, 0xF, 0xF, false));
    } else {  // R == 15
        return __int_as_float(__builtin_amdgcn_update_dpp(s, s, 0x140, 0xF, 0xF, false));
    }
}

// All-DPP shuffle: non-native XOR masks via 2-DPP composition (XOR a ^ b).
template<int R>
__device__ __forceinline__ float shuf(float x){
    if constexpr (R==1 || R==2 || R==3 || R==7 || R==8 || R==15){
        return xl<R>(x);
    } else if constexpr (R == 4){  return xl<3>(xl<7>(x));
    } else if constexpr (R == 5){  return xl<2>(xl<7>(x));
    } else if constexpr (R == 6){  return xl<1>(xl<7>(x));
    } else if constexpr (R == 9){  return xl<1>(xl<8>(x));
    } else if constexpr (R == 10){ return xl<2>(xl<8>(x));
    } else if constexpr (R == 11){ return xl<3>(xl<8>(x));
    } else if constexpr (R == 12){ return xl<3>(xl<15>(x));
    } else if constexpr (R == 13){ return xl<2>(xl<15>(x));
    } else {  /* R == 14 */        return xl<1>(xl<15>(x)); }
}

// decode linear lower-tri index d -> (r,c), d = r(r+1)/2 + c
__device__ __forceinline__ void tri_rc(int d, int &r, int &c){
    int rr = (int)floorf((sqrtf(fmaf(8.f, (float)d, 1.f)) - 1.f) * 0.5f);
    if (rr*(rr+1)/2 > d) rr--;
    if ((rr+1)*(rr+2)/2 <= d) rr++;
    r = rr; c = d - rr*(rr+1)/2;
}

// One XOR-tournament round of one-sided Jacobi. 16 lanes per matrix.
// Rotation from (d = nrm-pn, gam) with 2 rsq; per-lane sign automatic
// (d antisymmetric across the pair); wave-uniform noise-floor skip.
template<int R, bool WV>
__device__ __forceinline__ void jac_round(v2f* b, v2f* v, float &nrm, int t){
    v2f pc[8];
#pragma unroll
    for (int i = 0; i < 8; ++i){ pc[i].x = shuf<R>(b[i].x); pc[i].y = shuf<R>(b[i].y); }
    float pn = shuf<R>(nrm);
    v2f g2 = {0.f, 0.f};
#pragma unroll
    for (int i = 0; i < 8; ++i) g2 = g2 + b[i]*pc[i];
    float gam = g2.x + g2.y;
    // adaptive skip: |gam| <= 4e-7*sqrt(nrm*pn) is update-noise level; if every
    // pair in the wave (4 matrices) is there, the rotations are identity-level.
    bool live = (gam*gam > 1.6e-13f * (nrm * pn));
    if (__any((int)live)){
        constexpr int HB = (R & 8) ? 8 : ((R & 4) ? 4 : ((R & 2) ? 2 : 1));
        const bool isp = ((t & HB) == 0);
        // antisymmetric tie-break: if nrm==pn exactly, d still has opposite
        // signs in the two lanes of a pair.
        float d = (nrm - pn) + (isp ? 1e-30f : -1e-30f);
        float g22 = gam + gam;
        float nrr = fmaf(g22, g22, d*d);
        float inv_r = rsq_f(nrr);                      // 1/sqrt(d^2+4g^2)
        float c2 = fmaf(0.5f*fabsf(d), inv_r, 0.5f);   // cos^2(theta), >= 0.5
        float cinv = rsq_f(c2);
        float smag = fabsf(gam) * inv_r * cinv;        // |sin(theta)|
        int sgn = (__float_as_int(gam) ^ __float_as_int(d)) & 0x80000000;
        bool zn = (nrr == 0.f);                        // fully degenerate pair
        float c = zn ? 1.f : c2 * cinv;
        float s = zn ? 0.f : __int_as_float(__float_as_int(smag) | sgn);
        v2f cv = {c, c};
        v2f sv = {s, s};
#pragma unroll
        for (int i = 0; i < 8; ++i) b[i] = b[i]*cv + pc[i]*sv;
        if (WV){
            v2f pv[8];
#pragma unroll
            for (int i = 0; i < 8; ++i){ pv[i].x = shuf<R>(v[i].x); pv[i].y = shuf<R>(v[i].y); }
#pragma unroll
            for (int i = 0; i < 8; ++i) v[i] = v[i]*cv + pv[i]*sv;
        }
        nrm = fmaf(s * cinv, gam, nrm);                // alpha' = alpha + t*gam
    }
}

template<bool WV>
__device__ __forceinline__ void jac_sweep(v2f* b, v2f* v, float &nrm, int t){
    jac_round< 4,WV>(b,v,nrm,t); jac_round< 1,WV>(b,v,nrm,t);
    jac_round< 5,WV>(b,v,nrm,t); jac_round< 2,WV>(b,v,nrm,t);
    jac_round< 6,WV>(b,v,nrm,t); jac_round< 3,WV>(b,v,nrm,t);
    jac_round< 9,WV>(b,v,nrm,t); jac_round< 7,WV>(b,v,nrm,t);
    jac_round<10,WV>(b,v,nrm,t); jac_round< 8,WV>(b,v,nrm,t);
    jac_round<11,WV>(b,v,nrm,t); jac_round<15,WV>(b,v,nrm,t);
    jac_round<12,WV>(b,v,nrm,t); jac_round<13,WV>(b,v,nrm,t);
    jac_round<14,WV>(b,v,nrm,t);
}

// ---------------------------------------------------------------------------
// B: per-matrix eigh + logm lower triangle + per-block mean partials.
__global__ __launch_bounds__(256) void k_logm(const float* __restrict__ x,
                                              float* __restrict__ L,
                                              float* __restrict__ mpart,
                                              const float* __restrict__ W,
                                              const float* __restrict__ Wb,
                                              float* __restrict__ ws){
    __shared__ float sm[4608];     // Bl[16][272] + cof[16][16]  (18.4 KB)
    const int tid = threadIdx.x;
    const int t = tid & 15;
    const int g = tid >> 4;
    if (blockIdx.x == 6400){
        // ---- prep: s = svd(W_sym) desc -> G; WbT transpose ----
        float* sigv  = sm;          // 16
        float* s_srt = sm + 16;     // 16
        if (tid < 64){
            v2f b[8]; float nrm = 0.f;
            float* bf = (float*)b;
#pragma unroll
            for (int i = 0; i < 16; ++i){
                float val = 0.5f * (W[i*16 + t] + W[t*16 + i]);
                bf[i] = val;
                nrm = fmaf(val, val, nrm);
            }
#pragma unroll 1
            for (int sw = 0; sw < NSWEEP_SMALL; ++sw) jac_sweep<false>(b, b, nrm, t);
            float n2 = 0.f;
#pragma unroll
            for (int i = 0; i < 16; ++i) n2 = fmaf(bf[i], bf[i], n2);
            float sig = sqrtf(n2);
            if (tid < 16) sigv[t] = sig;
        }
        __syncthreads();
        if (tid < 16){
            float sig = sigv[t];
            int rank = 0;
#pragma unroll
            for (int u = 0; u < 16; ++u){
                float su = sigv[u];
                rank += (su > sig || (su == sig && u < t)) ? 1 : 0;
            }
            s_srt[rank] = sig;   // descending, matches jnp.linalg.svd order
        }
        for (int e = tid; e < 8768; e += 256){
            int o = e / 137, i = e - o*137;
            ws[OFF_WBT + i*64 + o] = Wb[e];
        }
        __syncthreads();
        if (tid < 136){
            int r, c; tri_rc(tid, r, c);
            float sr = s_srt[r], sc = s_srt[c];
            float den = sr - sc;
            bool eq = fabsf(den) < EPSV;
            float er = expf(sr), ec = expf(sc);
            float num = eq ? 0.5f*(er + ec) : (er - ec);
            float dd  = eq ? 1.f : den;
            float scale = (r == c) ? 1.f : SQRT2F;
            ws[OFF_G + tid] = scale * num / dd;
        }
        return;
    }
    float* Bl  = sm;               // g*272 + i*17 + t
    float* cof = sm + 4352;        // g*16 + j
    const size_t m = (size_t)blockIdx.x * 16 + g;
    const float* xp = x + m * 256;
    v2f b[8]; float nrm = 0.f;
    float* bf = (float*)b;
#pragma unroll
    for (int i = 0; i < 16; ++i){
        float val = xp[i*16 + t];
        bf[i] = val;
        nrm = fmaf(val, val, nrm);
    }
#pragma unroll 1
    for (int sw = 0; sw < NSWEEP_BIG; ++sw) jac_sweep<false>(b, b, nrm, t);
    float n2 = 0.f;
#pragma unroll
    for (int i = 0; i < 16; ++i) n2 = fmaf(bf[i], bf[i], n2);
    float lam = sqrtf(n2);
    float w = logf(fmaxf(lam, EPSV));
    float coef = w / n2;            // logm = sum_j coef_j b_j b_j^T
#pragma unroll
    for (int i = 0; i < 16; ++i) Bl[g*272 + i*17 + t] = bf[i];
    cof[g*16 + t] = coef;
    __syncthreads();
    float outv[9];
    float* Lp = L + m * 136;
#pragma unroll
    for (int k = 0; k < 9; ++k){
        int d = t + 16*k;
        float acc = 0.f;
        if (d < 136){
            int r, c; tri_rc(d, r, c);
#pragma unroll
            for (int j = 0; j < 16; ++j)
                acc = fmaf(cof[g*16 + j] * Bl[g*272 + r*17 + j], Bl[g*272 + c*17 + j], acc);
            Lp[d] = acc;
        }
        outv[k] = acc;
    }
    __syncthreads();
    float* red = sm;                // red[g*144 + d]
#pragma unroll
    for (int k = 0; k < 9; ++k){
        int d = t + 16*k;
        red[g*144 + d] = outv[k];
    }
    __syncthreads();
    if (tid < 136){
        float s = 0.f;
#pragma unroll
        for (int gg = 0; gg < 16; ++gg) s += red[gg*144 + tid];
        mpart[(size_t)blockIdx.x * 136 + tid] = s;
    }
}

// ---------------------------------------------------------------------------
// C: finalize mean from 200 block-partials per n.
__global__ __launch_bounds__(256) void k_xm_mean(float* __restrict__ ws){
    const int n = blockIdx.x;
    const int tid = threadIdx.x;
    if (tid < 136){
        const float* mp = ws + OFF_MPART + (size_t)n * 200 * 136 + tid;
        float s = 0.f;
#pragma unroll 4
        for (int c = 0; c < 200; ++c) s += mp[(size_t)c * 136];
        ws[OFF_MEAN + n*136 + tid] = s * (1.f/3200.f);
    }
}

// ---------------------------------------------------------------------------
// E: blocks 0..255: partial covariance. blocks 256..287: xm eigendecomp.
__global__ __launch_bounds__(512) void k_cov(float* __restrict__ ws){
    __shared__ __align__(16) float xc[16][136];
    __shared__ __align__(16) float Gl[136];
    __shared__ __align__(16) float Ml[136];
    const int bid = blockIdx.x;
    const int tid = threadIdx.x;
    if (bid >= 256){
        const int n = bid - 256;
        float* smf = &xc[0][0];
        float* Ms  = smf;              // 136
        float* Vl  = smf + 144;        // 16*20
        float* Hl2 = smf + 464;        // 16*20
        if (tid < 136) Ms[tid] = ws[OFF_MEAN + n*136 + tid];
        __syncthreads();
        const int t = tid & 15;
        if (tid < 64){
            v2f b[8], v[8]; float nrm = 0.f;
            float* bf = (float*)b;
            float* vf = (float*)v;
#pragma unroll
            for (int i = 0; i < 16; ++i){
                int r = (i > t) ? i : t, c = (i > t) ? t : i;
                bf[i] = Ms[r*(r+1)/2 + c];
                vf[i] = (i == t) ? 1.f : 0.f;
                nrm = fmaf(bf[i], bf[i], nrm);
            }
#pragma unroll 1
            for (int sw = 0; sw < NSWEEP_SMALL; ++sw) jac_sweep<true>(b, v, nrm, t);
            float lam = 0.f;
#pragma unroll
            for (int i = 0; i < 16; ++i) lam = fmaf(vf[i], bf[i], lam);  // signed
            float w = logf(fmaxf(lam, EPSV));
            if (tid < 16){
#pragma unroll
                for (int i = 0; i < 16; ++i){ Vl[i*20 + t] = vf[i]; Hl2[i*20 + t] = w * vf[i]; }
            }
        }
        __syncthreads();
        if (tid < 16){
            for (int k = 0; k < 9; ++k){
                int d = t + 16*k;
                if (d < 136){
                    int r, c; tri_rc(d, r, c);
                    float acc = 0.f;
#pragma unroll
                    for (int j = 0; j < 16; ++j) acc = fmaf(Hl2[r*20 + j], Vl[c*20 + j], acc);
                    float scale = (r == c) ? 1.f : SQRT2F;
                    ws[OFF_XM + n*136 + d] = scale * acc;
                }
            }
        }
        return;
    }
    const int n = bid & 31, c8 = bid >> 5;
    if (tid < 136){
        Gl[tid] = ws[OFF_G + tid];
        Ml[tid] = ws[OFF_MEAN + n*136 + tid];
    }
    int bi = 0, bj = 0; const bool val = (tid < 306);
    if (val){
        int T = tid;
        int bb = (int)floorf((sqrtf(fmaf(4.f, (float)T, 1.f)) - 1.f) * 0.5f);
        while (bb*bb + bb > T) bb--;
        while ((bb+1)*(bb+1) + (bb+1) <= T) bb++;
        bi = bb; bj = T - bb*bb - bb;
    }
    float a0[32];
#pragma unroll
    for (int i = 0; i < 32; ++i) a0[i] = 0.f;
    const float* Lbase = ws + OFF_L + (size_t)n * 3200 * 136;
    for (int st = 0; st < 25; ++st){
        __syncthreads();
        int p0 = c8*400 + st*16;
        for (int f = tid; f < 544; f += 512){
            int pp = f / 34, dd = f - pp*34;
            float4 lv = *(const float4*)(Lbase + (size_t)(p0+pp)*136 + dd*4);
            float4 gv = *(const float4*)(&Gl[dd*4]);
            float4 mv = *(const float4*)(&Ml[dd*4]);
            float4 r;
            r.x = (lv.x - mv.x) * gv.x; r.y = (lv.y - mv.y) * gv.y;
            r.z = (lv.z - mv.z) * gv.z; r.w = (lv.w - mv.w) * gv.w;
            *(float4*)(&xc[pp][dd*4]) = r;
        }
        __syncthreads();
        if (val){
#pragma unroll 1
            for (int pp = 0; pp < 16; ++pp){
                const float4 u0 = *(const float4*)(&xc[pp][bi*8]);
                const float4 u1 = *(const float4*)(&xc[pp][bi*8+4]);
                const float4 w4 = *(const float4*)(&xc[pp][bj*4]);
                float ui[8] = {u0.x,u0.y,u0.z,u0.w,u1.x,u1.y,u1.z,u1.w};
                float wj[4] = {w4.x,w4.y,w4.z,w4.w};
#pragma unroll
                for (int di = 0; di < 8; ++di)
#pragma unroll
                    for (int dj = 0; dj < 4; ++dj)
                        a0[di*4+dj] = fmaf(ui[di], wj[dj], a0[di*4+dj]);
            }
        }
    }
    if (val){
        float* part = ws + OFF_PART + ((size_t)c8*32 + n)*9316;
#pragma unroll
        for (int di = 0; di < 8; ++di){
            int i = bi*8 + di;
#pragma unroll
            for (int dj = 0; dj < 4; ++dj){
                int j = bj*4 + dj;
                if (j <= i) part[i*(i+1)/2 + j] = a0[di*4+dj];
            }
        }
    }
}

// ---------------------------------------------------------------------------
// F: sum partials -> cov (full-matrix LDS, stride 141) -> Cholesky -> write
//    tri-packed factor + trace to ws. Tout/bimap moved to k_tout/k_bimap.
#define TST 141   // T row stride: 141 mod 32 = 13, gcd(13,32)=1 -> conflict-free cols
__global__ __launch_bounds__(512) void k_chol(float* __restrict__ ws){
    __shared__ float T[136*TST];    // 76.7 KB
    __shared__ float ck[136];       // scaled column k (separate object: no aliasing)
    const int n = blockIdx.x;
    const int tid = threadIdx.x;
    // stage cov (tri-packed partials -> full lower)
    for (int e = tid; e < 9316; e += 512){
        float s = 0.f;
#pragma unroll
        for (int c = 0; c < 8; ++c) s += ws[OFF_PART + ((size_t)c*32 + n)*9316 + e];
        int r, cc2; tri_rc(e, r, cc2);
        T[r*TST + cc2] = s * (1.f/3199.f);
    }
    __syncthreads();
    // right-looking Cholesky on lower triangle
    for (int k = 0; k < 136; ++k){
        float d = sqrtf(T[k*TST + k]);
        float rinv = 1.f / d;
        {
            int i = k + 1 + tid;
            if (i < 136){
                float v2 = T[i*TST + k] * rinv;
                T[i*TST + k] = v2;
                ck[i] = v2;
            }
            if (tid == 0) T[k*TST + k] = d;
        }
        __syncthreads();
        const int m = 135 - k;
        const int cnt = m*(m+1)/2;
        const int Lc = (cnt + 511) >> 9;
        int e0 = tid * Lc, e1 = e0 + Lc; if (e1 > cnt) e1 = cnt;
        if (e0 < e1){
            float A = 2.f*m + 1.f;
            int jp = (int)floorf((A - sqrtf(fmaf(A, A, -8.f*e0))) * 0.5f);
            if (jp < 0) jp = 0;
            while (jp > 0 && jp*m - jp*(jp-1)/2 > e0) jp--;
            while ((jp+1)*m - (jp+1)*jp/2 <= e0) jp++;
            int ip = jp + (e0 - (jp*m - jp*(jp-1)/2));
            int i = k+1+ip, j = k+1+jp;
            int ix = i*TST + j;
            int e = e0;
            while (e < e1){
                int nb = e1 - e; if (nb > 8) nb = 8;
                int   ixs[8]; float cis[8], cjs[8], tv[8];
#pragma unroll
                for (int b2 = 0; b2 < 8; ++b2){
                    if (b2 < nb){
                        ixs[b2] = ix; cis[b2] = ck[i]; cjs[b2] = ck[j];
                        i++; ix += TST;
                        if (i == 136){ j++; i = j; ix = i*TST + j; }
                    }
                }
#pragma unroll
                for (int b2 = 0; b2 < 8; ++b2) if (b2 < nb) tv[b2] = T[ixs[b2]];
#pragma unroll
                for (int b2 = 0; b2 < 8; ++b2) if (b2 < nb) tv[b2] = fmaf(-cis[b2], cjs[b2], tv[b2]);
#pragma unroll
                for (int b2 = 0; b2 < 8; ++b2) if (b2 < nb) T[ixs[b2]] = tv[b2];
                e += nb;
            }
        }
        __syncthreads();
    }
    if (tid == 0){
        float tr = 1.f;
        for (int kk = 0; kk < 136; ++kk) tr += T[kk*TST + kk];
        ws[OFF_TR + n*2]     = tr;
        ws[OFF_TR + n*2 + 1] = 1.f / tr;
    }
    // write tri-packed factor (T stable since the k-loop's final barrier)
    for (int e = tid; e < 9316; e += 512){
        int r, c; tri_rc(e, r, c);
        ws[OFF_CT + (size_t)n*9320 + e] = T[r*TST + c];
    }
}

// ---------------------------------------------------------------------------
// F2: Tout rows. 256 blocks: n = bid>>3, s = bid&7 handles rows i = s+8k
//     (k=0..16), s==0 additionally row 136 (xm row). Writes Tt transposed:
//     ws[OFF_TT + n*8960 + q*140 + i].
__global__ __launch_bounds__(512) void k_tout(float* __restrict__ ws){
    __shared__ float Wt[8768];      // [j*64+q]
    __shared__ float tr_[1280];     // staged T rows (flat), max 1224 floats
    __shared__ float xs[137];
    const int bid = blockIdx.x;
    const int n = bid >> 3, s = bid & 7;
    const int tid = threadIdx.x;
    for (int e = tid; e < 8768; e += 512) Wt[e] = ws[OFF_WBT + e];
    const float* ct = ws + OFF_CT + (size_t)n * 9320;
    // stage rows i = s+8k at flat offset off(k) = k*(s+1) + 4k(k-1)
#pragma unroll 1
    for (int k = 0; k < 17; ++k){
        int i = s + 8*k;
        int off = k*(s+1) + 4*k*(k-1);
        int base = i*(i+1)/2;
        for (int e = tid; e <= i; e += 512) tr_[off + e] = ct[base + e];
    }
    if (tid < 137) xs[tid] = (tid < 136) ? ws[OFF_XM + n*136 + tid] : 1.f;
    __syncthreads();
    const float tr  = ws[OFF_TR + n*2];
    const float itr = ws[OFF_TR + n*2 + 1];
    const float c6 = tr * 1e-6f;
    const int q = tid & 63, w = tid >> 6;
    float* tt = ws + OFF_TT + (size_t)n * 8960;
#pragma unroll 1
    for (int k = w; k < 17; k += 8){
        int i = s + 8*k;
        int off = k*(s+1) + 4*k*(k-1);
        float acc = 0.f;
        for (int j = 0; j <= i; ++j) acc = fmaf(tr_[off + j], Wt[j*64 + q], acc);
        tt[q*140 + i] = fmaf(c6, Wt[i*64 + q], itr * acc);
    }
    if (s == 0 && w == 7){          // row 136: [xm | 1] row
        float acc = 0.f;
        for (int j = 0; j < 137; ++j) acc = fmaf(xs[j], Wt[j*64 + q], acc);
        tt[q*140 + 136] = fmaf(c6, Wt[136*64 + q], itr * acc);
    }
}

// ---------------------------------------------------------------------------
// F3: bimap. 256 blocks: n = bid>>3, s = bid&7 computes out rows o = s*8..s*8+7.
//     out[n][o][q] = sum_i Wb[o][i] * Tout[i][q], Tout read transposed (float4).
__global__ __launch_bounds__(512) void k_bimap(const float* __restrict__ ws,
                                               const float* __restrict__ Wb,
                                               float* __restrict__ out){
    __shared__ __align__(16) float Tl[8960];   // TtT: [q*140 + i]
    __shared__ __align__(16) float Wl[1120];   // 8 Wb rows at stride 140
    const int bid = blockIdx.x;
    const int n = bid >> 3, s = bid & 7;
    const int tid = threadIdx.x;
    const float* tt = ws + OFF_TT + (size_t)n * 8960;
    for (int e = tid*4; e < 8960; e += 2048)
        *(float4*)(Tl + e) = *(const float4*)(tt + e);
    for (int e = tid; e < 1096; e += 512){
        int o = e / 137, i = e - o*137;
        Wl[o*140 + i] = Wb[(s*8 + o)*137 + i];
    }
    __syncthreads();
    const int q = tid & 63, ol = tid >> 6;
    const float* tq = Tl + q*140;
    const float* wo = Wl + ol*140;
    float acc = 0.f;
#pragma unroll 1
    for (int i = 0; i < 136; i += 4){
        float4 tv = *(const float4*)(tq + i);
        float4 wv = *(const float4*)(wo + i);
        acc = fmaf(tv.x, wv.x, acc); acc = fmaf(tv.y, wv.y, acc);
        acc = fmaf(tv.z, wv.z, acc); acc = fmaf(tv.w, wv.w, acc);
    }
    acc = fmaf(tq[136], wo[136], acc);
    out[(size_t)n*4096 + (s*8 + ol)*64 + q] = acc;
}

// ---------------------------------------------------------------------------
extern "C" void kernel_launch(void* const* d_in, const int* in_sizes, int n_in,
                              void* d_out, int out_size, void* d_ws, size_t ws_size,
                              hipStream_t stream){
    const float* x   = (const float*)d_in[0];
    const float* W   = (const float*)d_in[1];
    const float* Wb  = (const float*)d_in[2];
    float* out = (float*)d_out;
    float* ws  = (float*)d_ws;

    k_logm   <<<6401, 256, 0, stream>>>(x, ws + OFF_L, ws + OFF_MPART, W, Wb, ws);
    k_xm_mean<<<  32, 256, 0, stream>>>(ws);
    k_cov    <<< 288, 512, 0, stream>>>(ws);
    k_chol   <<<  32, 512, 0, stream>>>(ws);
    k_tout   <<< 256, 512, 0, stream>>>(ws);
    k_bimap  <<< 256, 512, 0, stream>>>(ws, Wb, out);
}

// Round 3
// 755.144 us; speedup vs baseline: 1.1960x; 1.1960x over previous
//
#include <hip/hip_runtime.h>
#include <math.h>

// ---------------------------------------------------------------------------
// RiemannianPooling: logm(eigh) -> mean -> diff_exp -> cov -> cholesky -> bimap
// N=32, M*T*V=3200, C=16, D=136, out 32x64x64 fp32.
// R10: revert R9's all-DPP shuffles (regression: VALUBusy 97%, +30% VALU issue
//      — the ds_swizzle rounds were a DS/VALU pipe split, not a stall; with
//      ~6 waves/SIMD the crossbar dual-issues under other waves' VALU).
//      KEEP R9's k_chol split (k_chol -> factor only; k_tout/k_bimap at 256
//      blocks) — residual dropped 425 -> ~368 us.
//      jac_round rotation (2-rsq) + adaptive skip kept from R8.
// ---------------------------------------------------------------------------

#define EPSV 1e-4f
#define NSWEEP_BIG 6
#define NSWEEP_SMALL 10
#define SQRT2F 1.41421356237309515f

// workspace layout (float offsets) — total 66.5 MB
#define OFF_G      0            // 136
#define OFF_WBT    160          // 137*64 = 8768
#define OFF_MEAN   8960         // 32*136
#define OFF_XM     13312        // 32*136
#define OFF_TR     17664        // 32*2 (tr, 1/tr)
#define OFF_CT     17792        // 32*9320 tri-packed cholesky factor (ends 316032)
#define OFF_MPART  320000       // 6400*136 (aliases head of PART)
#define OFF_PART   320000       // 8*32*9316 (written after MPART consumed)
#define OFF_TT     320000       // 32*8960 Tout^T (aliases PART, dead after k_chol)
#define OFF_L      2704896      // 102400*136

typedef float v2f __attribute__((ext_vector_type(2)));

__device__ __forceinline__ float rcp_f(float x){ return __builtin_amdgcn_rcpf(x); }
__device__ __forceinline__ float rsq_f(float x){ return __builtin_amdgcn_rsqf(x); }

// XOR within 16-lane rows via single DPP (VALU pipe).
template<int R>
__device__ __forceinline__ float xl(float x){
    int s = __float_as_int(x);
    if constexpr (R == 1){
        return __int_as_float(__builtin_amdgcn_update_dpp(s, s, 0xB1, 0xF, 0xF, false));
    } else if constexpr (R == 2){
        return __int_as_float(__builtin_amdgcn_update_dpp(s, s, 0x4E, 0xF, 0xF, false));
    } else if constexpr (R == 3){
        return __int_as_float(__builtin_amdgcn_update_dpp(s, s, 0x1B, 0xF, 0xF, false));
    } else if constexpr (R == 7){
        return __int_as_float(__builtin_amdgcn_update_dpp(s, s, 0x141, 0xF, 0xF, false));
    } else if constexpr (R == 8){
        return __int_as_float(__builtin_amdgcn_update_dpp(s, s, 0x128, 0xF, 0xF, false));
    } else {  // R == 15
        return __int_as_float(__builtin_amdgcn_update_dpp(s, s, 0x140, 0xF, 0xF, false));
    }
}

// Pipe split: masks {4,5,6,9..14} -> DS crossbar; {1,2,3,7,8,15} on VALU DPP.
// (R9 post-mortem: DO NOT convert the DS ones to 2-DPP compositions — at
// ~90% VALUBusy with multi-wave occupancy the crossbar ops are free, and the
// composition adds ~30% VALU issue -> 375->540us regression.)
template<int R>
__device__ __forceinline__ float shuf(float x){
    if constexpr ((R >= 4 && R <= 6) || R >= 9){
        constexpr int IMM = (R << 10) | 0x1F;   // BitMode: xor=R, and=0x1F
        return __int_as_float(__builtin_amdgcn_ds_swizzle(__float_as_int(x), IMM));
    } else {
        return xl<R>(x);
    }
}

// decode linear lower-tri index d -> (r,c), d = r(r+1)/2 + c
__device__ __forceinline__ void tri_rc(int d, int &r, int &c){
    int rr = (int)floorf((sqrtf(fmaf(8.f, (float)d, 1.f)) - 1.f) * 0.5f);
    if (rr*(rr+1)/2 > d) rr--;
    if ((rr+1)*(rr+2)/2 <= d) rr++;
    r = rr; c = d - rr*(rr+1)/2;
}

// One XOR-tournament round of one-sided Jacobi. 16 lanes per matrix.
// Rotation from (d = nrm-pn, gam) with 2 rsq; per-lane sign automatic
// (d antisymmetric across the pair); wave-uniform noise-floor skip.
template<int R, bool WV>
__device__ __forceinline__ void jac_round(v2f* b, v2f* v, float &nrm, int t){
    v2f pc[8];
#pragma unroll
    for (int i = 0; i < 8; ++i){ pc[i].x = shuf<R>(b[i].x); pc[i].y = shuf<R>(b[i].y); }
    float pn = shuf<R>(nrm);
    v2f g2 = {0.f, 0.f};
#pragma unroll
    for (int i = 0; i < 8; ++i) g2 = g2 + b[i]*pc[i];
    float gam = g2.x + g2.y;
    // adaptive skip: |gam| <= 4e-7*sqrt(nrm*pn) is update-noise level; if every
    // pair in the wave (4 matrices) is there, the rotations are identity-level.
    bool live = (gam*gam > 1.6e-13f * (nrm * pn));
    if (__any((int)live)){
        constexpr int HB = (R & 8) ? 8 : ((R & 4) ? 4 : ((R & 2) ? 2 : 1));
        const bool isp = ((t & HB) == 0);
        // antisymmetric tie-break: if nrm==pn exactly, d still has opposite
        // signs in the two lanes of a pair.
        float d = (nrm - pn) + (isp ? 1e-30f : -1e-30f);
        float g22 = gam + gam;
        float nrr = fmaf(g22, g22, d*d);
        float inv_r = rsq_f(nrr);                      // 1/sqrt(d^2+4g^2)
        float c2 = fmaf(0.5f*fabsf(d), inv_r, 0.5f);   // cos^2(theta), >= 0.5
        float cinv = rsq_f(c2);
        float smag = fabsf(gam) * inv_r * cinv;        // |sin(theta)|
        int sgn = (__float_as_int(gam) ^ __float_as_int(d)) & 0x80000000;
        bool zn = (nrr == 0.f);                        // fully degenerate pair
        float c = zn ? 1.f : c2 * cinv;
        float s = zn ? 0.f : __int_as_float(__float_as_int(smag) | sgn);
        v2f cv = {c, c};
        v2f sv = {s, s};
#pragma unroll
        for (int i = 0; i < 8; ++i) b[i] = b[i]*cv + pc[i]*sv;
        if (WV){
            v2f pv[8];
#pragma unroll
            for (int i = 0; i < 8; ++i){ pv[i].x = shuf<R>(v[i].x); pv[i].y = shuf<R>(v[i].y); }
#pragma unroll
            for (int i = 0; i < 8; ++i) v[i] = v[i]*cv + pv[i]*sv;
        }
        nrm = fmaf(s * cinv, gam, nrm);                // alpha' = alpha + t*gam
    }
}

template<bool WV>
__device__ __forceinline__ void jac_sweep(v2f* b, v2f* v, float &nrm, int t){
    jac_round< 4,WV>(b,v,nrm,t); jac_round< 1,WV>(b,v,nrm,t);
    jac_round< 5,WV>(b,v,nrm,t); jac_round< 2,WV>(b,v,nrm,t);
    jac_round< 6,WV>(b,v,nrm,t); jac_round< 3,WV>(b,v,nrm,t);
    jac_round< 9,WV>(b,v,nrm,t); jac_round< 7,WV>(b,v,nrm,t);
    jac_round<10,WV>(b,v,nrm,t); jac_round< 8,WV>(b,v,nrm,t);
    jac_round<11,WV>(b,v,nrm,t); jac_round<15,WV>(b,v,nrm,t);
    jac_round<12,WV>(b,v,nrm,t); jac_round<13,WV>(b,v,nrm,t);
    jac_round<14,WV>(b,v,nrm,t);
}

// ---------------------------------------------------------------------------
// B: per-matrix eigh + logm lower triangle + per-block mean partials.
__global__ __launch_bounds__(256) void k_logm(const float* __restrict__ x,
                                              float* __restrict__ L,
                                              float* __restrict__ mpart,
                                              const float* __restrict__ W,
                                              const float* __restrict__ Wb,
                                              float* __restrict__ ws){
    __shared__ float sm[4608];     // Bl[16][272] + cof[16][16]  (18.4 KB)
    const int tid = threadIdx.x;
    const int t = tid & 15;
    const int g = tid >> 4;
    if (blockIdx.x == 6400){
        // ---- prep: s = svd(W_sym) desc -> G; WbT transpose ----
        float* sigv  = sm;          // 16
        float* s_srt = sm + 16;     // 16
        if (tid < 64){
            v2f b[8]; float nrm = 0.f;
            float* bf = (float*)b;
#pragma unroll
            for (int i = 0; i < 16; ++i){
                float val = 0.5f * (W[i*16 + t] + W[t*16 + i]);
                bf[i] = val;
                nrm = fmaf(val, val, nrm);
            }
#pragma unroll 1
            for (int sw = 0; sw < NSWEEP_SMALL; ++sw) jac_sweep<false>(b, b, nrm, t);
            float n2 = 0.f;
#pragma unroll
            for (int i = 0; i < 16; ++i) n2 = fmaf(bf[i], bf[i], n2);
            float sig = sqrtf(n2);
            if (tid < 16) sigv[t] = sig;
        }
        __syncthreads();
        if (tid < 16){
            float sig = sigv[t];
            int rank = 0;
#pragma unroll
            for (int u = 0; u < 16; ++u){
                float su = sigv[u];
                rank += (su > sig || (su == sig && u < t)) ? 1 : 0;
            }
            s_srt[rank] = sig;   // descending, matches jnp.linalg.svd order
        }
        for (int e = tid; e < 8768; e += 256){
            int o = e / 137, i = e - o*137;
            ws[OFF_WBT + i*64 + o] = Wb[e];
        }
        __syncthreads();
        if (tid < 136){
            int r, c; tri_rc(tid, r, c);
            float sr = s_srt[r], sc = s_srt[c];
            float den = sr - sc;
            bool eq = fabsf(den) < EPSV;
            float er = expf(sr), ec = expf(sc);
            float num = eq ? 0.5f*(er + ec) : (er - ec);
            float dd  = eq ? 1.f : den;
            float scale = (r == c) ? 1.f : SQRT2F;
            ws[OFF_G + tid] = scale * num / dd;
        }
        return;
    }
    float* Bl  = sm;               // g*272 + i*17 + t
    float* cof = sm + 4352;        // g*16 + j
    const size_t m = (size_t)blockIdx.x * 16 + g;
    const float* xp = x + m * 256;
    v2f b[8]; float nrm = 0.f;
    float* bf = (float*)b;
#pragma unroll
    for (int i = 0; i < 16; ++i){
        float val = xp[i*16 + t];
        bf[i] = val;
        nrm = fmaf(val, val, nrm);
    }
#pragma unroll 1
    for (int sw = 0; sw < NSWEEP_BIG; ++sw) jac_sweep<false>(b, b, nrm, t);
    float n2 = 0.f;
#pragma unroll
    for (int i = 0; i < 16; ++i) n2 = fmaf(bf[i], bf[i], n2);
    float lam = sqrtf(n2);
    float w = logf(fmaxf(lam, EPSV));
    float coef = w / n2;            // logm = sum_j coef_j b_j b_j^T
#pragma unroll
    for (int i = 0; i < 16; ++i) Bl[g*272 + i*17 + t] = bf[i];
    cof[g*16 + t] = coef;
    __syncthreads();
    float outv[9];
    float* Lp = L + m * 136;
#pragma unroll
    for (int k = 0; k < 9; ++k){
        int d = t + 16*k;
        float acc = 0.f;
        if (d < 136){
            int r, c; tri_rc(d, r, c);
#pragma unroll
            for (int j = 0; j < 16; ++j)
                acc = fmaf(cof[g*16 + j] * Bl[g*272 + r*17 + j], Bl[g*272 + c*17 + j], acc);
            Lp[d] = acc;
        }
        outv[k] = acc;
    }
    __syncthreads();
    float* red = sm;                // red[g*144 + d]
#pragma unroll
    for (int k = 0; k < 9; ++k){
        int d = t + 16*k;
        red[g*144 + d] = outv[k];
    }
    __syncthreads();
    if (tid < 136){
        float s = 0.f;
#pragma unroll
        for (int gg = 0; gg < 16; ++gg) s += red[gg*144 + tid];
        mpart[(size_t)blockIdx.x * 136 + tid] = s;
    }
}

// ---------------------------------------------------------------------------
// C: finalize mean from 200 block-partials per n.
__global__ __launch_bounds__(256) void k_xm_mean(float* __restrict__ ws){
    const int n = blockIdx.x;
    const int tid = threadIdx.x;
    if (tid < 136){
        const float* mp = ws + OFF_MPART + (size_t)n * 200 * 136 + tid;
        float s = 0.f;
#pragma unroll 4
        for (int c = 0; c < 200; ++c) s += mp[(size_t)c * 136];
        ws[OFF_MEAN + n*136 + tid] = s * (1.f/3200.f);
    }
}

// ---------------------------------------------------------------------------
// E: blocks 0..255: partial covariance. blocks 256..287: xm eigendecomp.
__global__ __launch_bounds__(512) void k_cov(float* __restrict__ ws){
    __shared__ __align__(16) float xc[16][136];
    __shared__ __align__(16) float Gl[136];
    __shared__ __align__(16) float Ml[136];
    const int bid = blockIdx.x;
    const int tid = threadIdx.x;
    if (bid >= 256){
        const int n = bid - 256;
        float* smf = &xc[0][0];
        float* Ms  = smf;              // 136
        float* Vl  = smf + 144;        // 16*20
        float* Hl2 = smf + 464;        // 16*20
        if (tid < 136) Ms[tid] = ws[OFF_MEAN + n*136 + tid];
        __syncthreads();
        const int t = tid & 15;
        if (tid < 64){
            v2f b[8], v[8]; float nrm = 0.f;
            float* bf = (float*)b;
            float* vf = (float*)v;
#pragma unroll
            for (int i = 0; i < 16; ++i){
                int r = (i > t) ? i : t, c = (i > t) ? t : i;
                bf[i] = Ms[r*(r+1)/2 + c];
                vf[i] = (i == t) ? 1.f : 0.f;
                nrm = fmaf(bf[i], bf[i], nrm);
            }
#pragma unroll 1
            for (int sw = 0; sw < NSWEEP_SMALL; ++sw) jac_sweep<true>(b, v, nrm, t);
            float lam = 0.f;
#pragma unroll
            for (int i = 0; i < 16; ++i) lam = fmaf(vf[i], bf[i], lam);  // signed
            float w = logf(fmaxf(lam, EPSV));
            if (tid < 16){
#pragma unroll
                for (int i = 0; i < 16; ++i){ Vl[i*20 + t] = vf[i]; Hl2[i*20 + t] = w * vf[i]; }
            }
        }
        __syncthreads();
        if (tid < 16){
            for (int k = 0; k < 9; ++k){
                int d = t + 16*k;
                if (d < 136){
                    int r, c; tri_rc(d, r, c);
                    float acc = 0.f;
#pragma unroll
                    for (int j = 0; j < 16; ++j) acc = fmaf(Hl2[r*20 + j], Vl[c*20 + j], acc);
                    float scale = (r == c) ? 1.f : SQRT2F;
                    ws[OFF_XM + n*136 + d] = scale * acc;
                }
            }
        }
        return;
    }
    const int n = bid & 31, c8 = bid >> 5;
    if (tid < 136){
        Gl[tid] = ws[OFF_G + tid];
        Ml[tid] = ws[OFF_MEAN + n*136 + tid];
    }
    int bi = 0, bj = 0; const bool val = (tid < 306);
    if (val){
        int T = tid;
        int bb = (int)floorf((sqrtf(fmaf(4.f, (float)T, 1.f)) - 1.f) * 0.5f);
        while (bb*bb + bb > T) bb--;
        while ((bb+1)*(bb+1) + (bb+1) <= T) bb++;
        bi = bb; bj = T - bb*bb - bb;
    }
    float a0[32];
#pragma unroll
    for (int i = 0; i < 32; ++i) a0[i] = 0.f;
    const float* Lbase = ws + OFF_L + (size_t)n * 3200 * 136;
    for (int st = 0; st < 25; ++st){
        __syncthreads();
        int p0 = c8*400 + st*16;
        for (int f = tid; f < 544; f += 512){
            int pp = f / 34, dd = f - pp*34;
            float4 lv = *(const float4*)(Lbase + (size_t)(p0+pp)*136 + dd*4);
            float4 gv = *(const float4*)(&Gl[dd*4]);
            float4 mv = *(const float4*)(&Ml[dd*4]);
            float4 r;
            r.x = (lv.x - mv.x) * gv.x; r.y = (lv.y - mv.y) * gv.y;
            r.z = (lv.z - mv.z) * gv.z; r.w = (lv.w - mv.w) * gv.w;
            *(float4*)(&xc[pp][dd*4]) = r;
        }
        __syncthreads();
        if (val){
#pragma unroll 1
            for (int pp = 0; pp < 16; ++pp){
                const float4 u0 = *(const float4*)(&xc[pp][bi*8]);
                const float4 u1 = *(const float4*)(&xc[pp][bi*8+4]);
                const float4 w4 = *(const float4*)(&xc[pp][bj*4]);
                float ui[8] = {u0.x,u0.y,u0.z,u0.w,u1.x,u1.y,u1.z,u1.w};
                float wj[4] = {w4.x,w4.y,w4.z,w4.w};
#pragma unroll
                for (int di = 0; di < 8; ++di)
#pragma unroll
                    for (int dj = 0; dj < 4; ++dj)
                        a0[di*4+dj] = fmaf(ui[di], wj[dj], a0[di*4+dj]);
            }
        }
    }
    if (val){
        float* part = ws + OFF_PART + ((size_t)c8*32 + n)*9316;
#pragma unroll
        for (int di = 0; di < 8; ++di){
            int i = bi*8 + di;
#pragma unroll
            for (int dj = 0; dj < 4; ++dj){
                int j = bj*4 + dj;
                if (j <= i) part[i*(i+1)/2 + j] = a0[di*4+dj];
            }
        }
    }
}

// ---------------------------------------------------------------------------
// F: sum partials -> cov (full-matrix LDS, stride 141) -> Cholesky -> write
//    tri-packed factor + trace to ws. Tout/bimap moved to k_tout/k_bimap.
#define TST 141   // T row stride: 141 mod 32 = 13, gcd(13,32)=1 -> conflict-free cols
__global__ __launch_bounds__(512) void k_chol(float* __restrict__ ws){
    __shared__ float T[136*TST];    // 76.7 KB
    __shared__ float ck[136];       // scaled column k (separate object: no aliasing)
    const int n = blockIdx.x;
    const int tid = threadIdx.x;
    // stage cov (tri-packed partials -> full lower)
    for (int e = tid; e < 9316; e += 512){
        float s = 0.f;
#pragma unroll
        for (int c = 0; c < 8; ++c) s += ws[OFF_PART + ((size_t)c*32 + n)*9316 + e];
        int r, cc2; tri_rc(e, r, cc2);
        T[r*TST + cc2] = s * (1.f/3199.f);
    }
    __syncthreads();
    // right-looking Cholesky on lower triangle
    for (int k = 0; k < 136; ++k){
        float d = sqrtf(T[k*TST + k]);
        float rinv = 1.f / d;
        {
            int i = k + 1 + tid;
            if (i < 136){
                float v2 = T[i*TST + k] * rinv;
                T[i*TST + k] = v2;
                ck[i] = v2;
            }
            if (tid == 0) T[k*TST + k] = d;
        }
        __syncthreads();
        const int m = 135 - k;
        const int cnt = m*(m+1)/2;
        const int Lc = (cnt + 511) >> 9;
        int e0 = tid * Lc, e1 = e0 + Lc; if (e1 > cnt) e1 = cnt;
        if (e0 < e1){
            float A = 2.f*m + 1.f;
            int jp = (int)floorf((A - sqrtf(fmaf(A, A, -8.f*e0))) * 0.5f);
            if (jp < 0) jp = 0;
            while (jp > 0 && jp*m - jp*(jp-1)/2 > e0) jp--;
            while ((jp+1)*m - (jp+1)*jp/2 <= e0) jp++;
            int ip = jp + (e0 - (jp*m - jp*(jp-1)/2));
            int i = k+1+ip, j = k+1+jp;
            int ix = i*TST + j;
            int e = e0;
            while (e < e1){
                int nb = e1 - e; if (nb > 8) nb = 8;
                int   ixs[8]; float cis[8], cjs[8], tv[8];
#pragma unroll
                for (int b2 = 0; b2 < 8; ++b2){
                    if (b2 < nb){
                        ixs[b2] = ix; cis[b2] = ck[i]; cjs[b2] = ck[j];
                        i++; ix += TST;
                        if (i == 136){ j++; i = j; ix = i*TST + j; }
                    }
                }
#pragma unroll
                for (int b2 = 0; b2 < 8; ++b2) if (b2 < nb) tv[b2] = T[ixs[b2]];
#pragma unroll
                for (int b2 = 0; b2 < 8; ++b2) if (b2 < nb) tv[b2] = fmaf(-cis[b2], cjs[b2], tv[b2]);
#pragma unroll
                for (int b2 = 0; b2 < 8; ++b2) if (b2 < nb) T[ixs[b2]] = tv[b2];
                e += nb;
            }
        }
        __syncthreads();
    }
    if (tid == 0){
        float tr = 1.f;
        for (int kk = 0; kk < 136; ++kk) tr += T[kk*TST + kk];
        ws[OFF_TR + n*2]     = tr;
        ws[OFF_TR + n*2 + 1] = 1.f / tr;
    }
    // write tri-packed factor (T stable since the k-loop's final barrier)
    for (int e = tid; e < 9316; e += 512){
        int r, c; tri_rc(e, r, c);
        ws[OFF_CT + (size_t)n*9320 + e] = T[r*TST + c];
    }
}

// ---------------------------------------------------------------------------
// F2: Tout rows. 256 blocks: n = bid>>3, s = bid&7 handles rows i = s+8k
//     (k=0..16), s==0 additionally row 136 (xm row). Writes Tt transposed:
//     ws[OFF_TT + n*8960 + q*140 + i].
__global__ __launch_bounds__(512) void k_tout(float* __restrict__ ws){
    __shared__ float Wt[8768];      // [j*64+q]
    __shared__ float tr_[1280];     // staged T rows (flat), max 1224 floats
    __shared__ float xs[137];
    const int bid = blockIdx.x;
    const int n = bid >> 3, s = bid & 7;
    const int tid = threadIdx.x;
    for (int e = tid; e < 8768; e += 512) Wt[e] = ws[OFF_WBT + e];
    const float* ct = ws + OFF_CT + (size_t)n * 9320;
    // stage rows i = s+8k at flat offset off(k) = k*(s+1) + 4k(k-1)
#pragma unroll 1
    for (int k = 0; k < 17; ++k){
        int i = s + 8*k;
        int off = k*(s+1) + 4*k*(k-1);
        int base = i*(i+1)/2;
        for (int e = tid; e <= i; e += 512) tr_[off + e] = ct[base + e];
    }
    if (tid < 137) xs[tid] = (tid < 136) ? ws[OFF_XM + n*136 + tid] : 1.f;
    __syncthreads();
    const float tr  = ws[OFF_TR + n*2];
    const float itr = ws[OFF_TR + n*2 + 1];
    const float c6 = tr * 1e-6f;
    const int q = tid & 63, w = tid >> 6;
    float* tt = ws + OFF_TT + (size_t)n * 8960;
#pragma unroll 1
    for (int k = w; k < 17; k += 8){
        int i = s + 8*k;
        int off = k*(s+1) + 4*k*(k-1);
        float acc = 0.f;
        for (int j = 0; j <= i; ++j) acc = fmaf(tr_[off + j], Wt[j*64 + q], acc);
        tt[q*140 + i] = fmaf(c6, Wt[i*64 + q], itr * acc);
    }
    if (s == 0 && w == 7){          // row 136: [xm | 1] row
        float acc = 0.f;
        for (int j = 0; j < 137; ++j) acc = fmaf(xs[j], Wt[j*64 + q], acc);
        tt[q*140 + 136] = fmaf(c6, Wt[136*64 + q], itr * acc);
    }
}

// ---------------------------------------------------------------------------
// F3: bimap. 256 blocks: n = bid>>3, s = bid&7 computes out rows o = s*8..s*8+7.
//     out[n][o][q] = sum_i Wb[o][i] * Tout[i][q], Tout read transposed (float4).
__global__ __launch_bounds__(512) void k_bimap(const float* __restrict__ ws,
                                               const float* __restrict__ Wb,
                                               float* __restrict__ out){
    __shared__ __align__(16) float Tl[8960];   // TtT: [q*140 + i]
    __shared__ __align__(16) float Wl[1120];   // 8 Wb rows at stride 140
    const int bid = blockIdx.x;
    const int n = bid >> 3, s = bid & 7;
    const int tid = threadIdx.x;
    const float* tt = ws + OFF_TT + (size_t)n * 8960;
    for (int e = tid*4; e < 8960; e += 2048)
        *(float4*)(Tl + e) = *(const float4*)(tt + e);
    for (int e = tid; e < 1096; e += 512){
        int o = e / 137, i = e - o*137;
        Wl[o*140 + i] = Wb[(s*8 + o)*137 + i];
    }
    __syncthreads();
    const int q = tid & 63, ol = tid >> 6;
    const float* tq = Tl + q*140;
    const float* wo = Wl + ol*140;
    float acc = 0.f;
#pragma unroll 1
    for (int i = 0; i < 136; i += 4){
        float4 tv = *(const float4*)(tq + i);
        float4 wv = *(const float4*)(wo + i);
        acc = fmaf(tv.x, wv.x, acc); acc = fmaf(tv.y, wv.y, acc);
        acc = fmaf(tv.z, wv.z, acc); acc = fmaf(tv.w, wv.w, acc);
    }
    acc = fmaf(tq[136], wo[136], acc);
    out[(size_t)n*4096 + (s*8 + ol)*64 + q] = acc;
}

// ---------------------------------------------------------------------------
extern "C" void kernel_launch(void* const* d_in, const int* in_sizes, int n_in,
                              void* d_out, int out_size, void* d_ws, size_t ws_size,
                              hipStream_t stream){
    const float* x   = (const float*)d_in[0];
    const float* W   = (const float*)d_in[1];
    const float* Wb  = (const float*)d_in[2];
    float* out = (float*)d_out;
    float* ws  = (float*)d_ws;

    k_logm   <<<6401, 256, 0, stream>>>(x, ws + OFF_L, ws + OFF_MPART, W, Wb, ws);
    k_xm_mean<<<  32, 256, 0, stream>>>(ws);
    k_cov    <<< 288, 512, 0, stream>>>(ws);
    k_chol   <<<  32, 512, 0, stream>>>(ws);
    k_tout   <<< 256, 512, 0, stream>>>(ws);
    k_bimap  <<< 256, 512, 0, stream>>>(ws, Wb, out);
}

// Round 4
// 745.550 us; speedup vs baseline: 1.2114x; 1.0129x over previous
//
#include <hip/hip_runtime.h>
#include <math.h>

// ---------------------------------------------------------------------------
// RiemannianPooling: logm(eigh) -> mean -> diff_exp -> cov -> cholesky -> bimap
// N=32, M*T*V=3200, C=16, D=136, out 32x64x64 fp32.
// R11: packed-FP32 (v_pk_fma_f32 / v_pk_mul_f32 via inline asm — compiler does
//      not form VOP3P from v2f arithmetic) in the two VALU-hot loops:
//      (1) jac_round: Gram dot 16 fma -> 8 pk_fma (2 accumulators, chain
//          32->16 cy); update 32 ops -> 16 pk ops. ~-30% VALU instr/round.
//      (2) k_cov: 32 fma/pp -> 16 pk_fma + 4 movs (di-pairs free from float4).
//      Shuffle pipe-split (DS/DPP) and all structure frozen from R10.
// ---------------------------------------------------------------------------

#define EPSV 1e-4f
#define NSWEEP_BIG 6
#define NSWEEP_SMALL 10
#define SQRT2F 1.41421356237309515f

// workspace layout (float offsets) — total 66.5 MB
#define OFF_G      0            // 136
#define OFF_WBT    160          // 137*64 = 8768
#define OFF_MEAN   8960         // 32*136
#define OFF_XM     13312        // 32*136
#define OFF_TR     17664        // 32*2 (tr, 1/tr)
#define OFF_CT     17792        // 32*9320 tri-packed cholesky factor (ends 316032)
#define OFF_MPART  320000       // 6400*136 (aliases head of PART)
#define OFF_PART   320000       // 8*32*9316 (written after MPART consumed)
#define OFF_TT     320000       // 32*8960 Tout^T (aliases PART, dead after k_chol)
#define OFF_L      2704896      // 102400*136

typedef float v2f __attribute__((ext_vector_type(2)));

__device__ __forceinline__ float rcp_f(float x){ return __builtin_amdgcn_rcpf(x); }
__device__ __forceinline__ float rsq_f(float x){ return __builtin_amdgcn_rsqf(x); }

// Packed fp32 (VOP3P). gfx950's 157.3 TF fp32 peak is the packed rate; the
// compiler scalarizes v2f arithmetic, so emit these explicitly.
__device__ __forceinline__ v2f pk_fma(v2f a, v2f b, v2f c){
    v2f d;
    asm("v_pk_fma_f32 %0, %1, %2, %3" : "=v"(d) : "v"(a), "v"(b), "v"(c));
    return d;
}
__device__ __forceinline__ v2f pk_mul(v2f a, v2f b){
    v2f d;
    asm("v_pk_mul_f32 %0, %1, %2" : "=v"(d) : "v"(a), "v"(b));
    return d;
}

// XOR within 16-lane rows via single DPP (VALU pipe).
template<int R>
__device__ __forceinline__ float xl(float x){
    int s = __float_as_int(x);
    if constexpr (R == 1){
        return __int_as_float(__builtin_amdgcn_update_dpp(s, s, 0xB1, 0xF, 0xF, false));
    } else if constexpr (R == 2){
        return __int_as_float(__builtin_amdgcn_update_dpp(s, s, 0x4E, 0xF, 0xF, false));
    } else if constexpr (R == 3){
        return __int_as_float(__builtin_amdgcn_update_dpp(s, s, 0x1B, 0xF, 0xF, false));
    } else if constexpr (R == 7){
        return __int_as_float(__builtin_amdgcn_update_dpp(s, s, 0x141, 0xF, 0xF, false));
    } else if constexpr (R == 8){
        return __int_as_float(__builtin_amdgcn_update_dpp(s, s, 0x128, 0xF, 0xF, false));
    } else {  // R == 15
        return __int_as_float(__builtin_amdgcn_update_dpp(s, s, 0x140, 0xF, 0xF, false));
    }
}

// Pipe split: masks {4,5,6,9..14} -> DS crossbar; {1,2,3,7,8,15} on VALU DPP.
// (R9 post-mortem: DO NOT convert the DS ones to 2-DPP compositions — at
// high VALU pressure with multi-wave occupancy the crossbar ops are free, and
// the composition adds ~30% VALU issue -> 375->540us regression.)
template<int R>
__device__ __forceinline__ float shuf(float x){
    if constexpr ((R >= 4 && R <= 6) || R >= 9){
        constexpr int IMM = (R << 10) | 0x1F;   // BitMode: xor=R, and=0x1F
        return __int_as_float(__builtin_amdgcn_ds_swizzle(__float_as_int(x), IMM));
    } else {
        return xl<R>(x);
    }
}

// decode linear lower-tri index d -> (r,c), d = r(r+1)/2 + c
__device__ __forceinline__ void tri_rc(int d, int &r, int &c){
    int rr = (int)floorf((sqrtf(fmaf(8.f, (float)d, 1.f)) - 1.f) * 0.5f);
    if (rr*(rr+1)/2 > d) rr--;
    if ((rr+1)*(rr+2)/2 <= d) rr++;
    r = rr; c = d - rr*(rr+1)/2;
}

// One XOR-tournament round of one-sided Jacobi. 16 lanes per matrix.
// Rotation from (d = nrm-pn, gam) with 2 rsq; per-lane sign automatic
// (d antisymmetric across the pair); wave-uniform noise-floor skip.
template<int R, bool WV>
__device__ __forceinline__ void jac_round(v2f* b, v2f* v, float &nrm, int t){
    v2f pc[8];
#pragma unroll
    for (int i = 0; i < 8; ++i){ pc[i].x = shuf<R>(b[i].x); pc[i].y = shuf<R>(b[i].y); }
    float pn = shuf<R>(nrm);
    // Gram dot: 8 pk_fma in 2 chains (4-deep) instead of 16 scalar fma.
    v2f ga = pk_mul(b[0], pc[0]);
    v2f gb = pk_mul(b[1], pc[1]);
    ga = pk_fma(b[2], pc[2], ga); gb = pk_fma(b[3], pc[3], gb);
    ga = pk_fma(b[4], pc[4], ga); gb = pk_fma(b[5], pc[5], gb);
    ga = pk_fma(b[6], pc[6], ga); gb = pk_fma(b[7], pc[7], gb);
    float gam = (ga.x + gb.x) + (ga.y + gb.y);
    // adaptive skip: |gam| <= 4e-7*sqrt(nrm*pn) is update-noise level; if every
    // pair in the wave (4 matrices) is there, the rotations are identity-level.
    bool live = (gam*gam > 1.6e-13f * (nrm * pn));
    if (__any((int)live)){
        constexpr int HB = (R & 8) ? 8 : ((R & 4) ? 4 : ((R & 2) ? 2 : 1));
        const bool isp = ((t & HB) == 0);
        // antisymmetric tie-break: if nrm==pn exactly, d still has opposite
        // signs in the two lanes of a pair.
        float d = (nrm - pn) + (isp ? 1e-30f : -1e-30f);
        float g22 = gam + gam;
        float nrr = fmaf(g22, g22, d*d);
        float inv_r = rsq_f(nrr);                      // 1/sqrt(d^2+4g^2)
        float c2 = fmaf(0.5f*fabsf(d), inv_r, 0.5f);   // cos^2(theta), >= 0.5
        float cinv = rsq_f(c2);
        float smag = fabsf(gam) * inv_r * cinv;        // |sin(theta)|
        int sgn = (__float_as_int(gam) ^ __float_as_int(d)) & 0x80000000;
        bool zn = (nrr == 0.f);                        // fully degenerate pair
        float c = zn ? 1.f : c2 * cinv;
        float s = zn ? 0.f : __int_as_float(__float_as_int(smag) | sgn);
        v2f cv = {c, c};
        v2f sv = {s, s};
#pragma unroll
        for (int i = 0; i < 8; ++i) b[i] = pk_fma(pc[i], sv, pk_mul(b[i], cv));
        if (WV){
            v2f pv[8];
#pragma unroll
            for (int i = 0; i < 8; ++i){ pv[i].x = shuf<R>(v[i].x); pv[i].y = shuf<R>(v[i].y); }
#pragma unroll
            for (int i = 0; i < 8; ++i) v[i] = pk_fma(pv[i], sv, pk_mul(v[i], cv));
        }
        nrm = fmaf(s * cinv, gam, nrm);                // alpha' = alpha + t*gam
    }
}

template<bool WV>
__device__ __forceinline__ void jac_sweep(v2f* b, v2f* v, float &nrm, int t){
    jac_round< 4,WV>(b,v,nrm,t); jac_round< 1,WV>(b,v,nrm,t);
    jac_round< 5,WV>(b,v,nrm,t); jac_round< 2,WV>(b,v,nrm,t);
    jac_round< 6,WV>(b,v,nrm,t); jac_round< 3,WV>(b,v,nrm,t);
    jac_round< 9,WV>(b,v,nrm,t); jac_round< 7,WV>(b,v,nrm,t);
    jac_round<10,WV>(b,v,nrm,t); jac_round< 8,WV>(b,v,nrm,t);
    jac_round<11,WV>(b,v,nrm,t); jac_round<15,WV>(b,v,nrm,t);
    jac_round<12,WV>(b,v,nrm,t); jac_round<13,WV>(b,v,nrm,t);
    jac_round<14,WV>(b,v,nrm,t);
}

// ---------------------------------------------------------------------------
// B: per-matrix eigh + logm lower triangle + per-block mean partials.
__global__ __launch_bounds__(256) void k_logm(const float* __restrict__ x,
                                              float* __restrict__ L,
                                              float* __restrict__ mpart,
                                              const float* __restrict__ W,
                                              const float* __restrict__ Wb,
                                              float* __restrict__ ws){
    __shared__ float sm[4608];     // Bl[16][272] + cof[16][16]  (18.4 KB)
    const int tid = threadIdx.x;
    const int t = tid & 15;
    const int g = tid >> 4;
    if (blockIdx.x == 6400){
        // ---- prep: s = svd(W_sym) desc -> G; WbT transpose ----
        float* sigv  = sm;          // 16
        float* s_srt = sm + 16;     // 16
        if (tid < 64){
            v2f b[8]; float nrm = 0.f;
            float* bf = (float*)b;
#pragma unroll
            for (int i = 0; i < 16; ++i){
                float val = 0.5f * (W[i*16 + t] + W[t*16 + i]);
                bf[i] = val;
                nrm = fmaf(val, val, nrm);
            }
#pragma unroll 1
            for (int sw = 0; sw < NSWEEP_SMALL; ++sw) jac_sweep<false>(b, b, nrm, t);
            float n2 = 0.f;
#pragma unroll
            for (int i = 0; i < 16; ++i) n2 = fmaf(bf[i], bf[i], n2);
            float sig = sqrtf(n2);
            if (tid < 16) sigv[t] = sig;
        }
        __syncthreads();
        if (tid < 16){
            float sig = sigv[t];
            int rank = 0;
#pragma unroll
            for (int u = 0; u < 16; ++u){
                float su = sigv[u];
                rank += (su > sig || (su == sig && u < t)) ? 1 : 0;
            }
            s_srt[rank] = sig;   // descending, matches jnp.linalg.svd order
        }
        for (int e = tid; e < 8768; e += 256){
            int o = e / 137, i = e - o*137;
            ws[OFF_WBT + i*64 + o] = Wb[e];
        }
        __syncthreads();
        if (tid < 136){
            int r, c; tri_rc(tid, r, c);
            float sr = s_srt[r], sc = s_srt[c];
            float den = sr - sc;
            bool eq = fabsf(den) < EPSV;
            float er = expf(sr), ec = expf(sc);
            float num = eq ? 0.5f*(er + ec) : (er - ec);
            float dd  = eq ? 1.f : den;
            float scale = (r == c) ? 1.f : SQRT2F;
            ws[OFF_G + tid] = scale * num / dd;
        }
        return;
    }
    float* Bl  = sm;               // g*272 + i*17 + t
    float* cof = sm + 4352;        // g*16 + j
    const size_t m = (size_t)blockIdx.x * 16 + g;
    const float* xp = x + m * 256;
    v2f b[8]; float nrm = 0.f;
    float* bf = (float*)b;
#pragma unroll
    for (int i = 0; i < 16; ++i){
        float val = xp[i*16 + t];
        bf[i] = val;
        nrm = fmaf(val, val, nrm);
    }
#pragma unroll 1
    for (int sw = 0; sw < NSWEEP_BIG; ++sw) jac_sweep<false>(b, b, nrm, t);
    float n2 = 0.f;
#pragma unroll
    for (int i = 0; i < 16; ++i) n2 = fmaf(bf[i], bf[i], n2);
    float lam = sqrtf(n2);
    float w = logf(fmaxf(lam, EPSV));
    float coef = w / n2;            // logm = sum_j coef_j b_j b_j^T
#pragma unroll
    for (int i = 0; i < 16; ++i) Bl[g*272 + i*17 + t] = bf[i];
    cof[g*16 + t] = coef;
    __syncthreads();
    float outv[9];
    float* Lp = L + m * 136;
#pragma unroll
    for (int k = 0; k < 9; ++k){
        int d = t + 16*k;
        float acc = 0.f;
        if (d < 136){
            int r, c; tri_rc(d, r, c);
#pragma unroll
            for (int j = 0; j < 16; ++j)
                acc = fmaf(cof[g*16 + j] * Bl[g*272 + r*17 + j], Bl[g*272 + c*17 + j], acc);
            Lp[d] = acc;
        }
        outv[k] = acc;
    }
    __syncthreads();
    float* red = sm;                // red[g*144 + d]
#pragma unroll
    for (int k = 0; k < 9; ++k){
        int d = t + 16*k;
        red[g*144 + d] = outv[k];
    }
    __syncthreads();
    if (tid < 136){
        float s = 0.f;
#pragma unroll
        for (int gg = 0; gg < 16; ++gg) s += red[gg*144 + tid];
        mpart[(size_t)blockIdx.x * 136 + tid] = s;
    }
}

// ---------------------------------------------------------------------------
// C: finalize mean from 200 block-partials per n.
__global__ __launch_bounds__(256) void k_xm_mean(float* __restrict__ ws){
    const int n = blockIdx.x;
    const int tid = threadIdx.x;
    if (tid < 136){
        const float* mp = ws + OFF_MPART + (size_t)n * 200 * 136 + tid;
        float s = 0.f;
#pragma unroll 4
        for (int c = 0; c < 200; ++c) s += mp[(size_t)c * 136];
        ws[OFF_MEAN + n*136 + tid] = s * (1.f/3200.f);
    }
}

// ---------------------------------------------------------------------------
// E: blocks 0..255: partial covariance. blocks 256..287: xm eigendecomp.
__global__ __launch_bounds__(512) void k_cov(float* __restrict__ ws){
    __shared__ __align__(16) float xc[16][136];
    __shared__ __align__(16) float Gl[136];
    __shared__ __align__(16) float Ml[136];
    const int bid = blockIdx.x;
    const int tid = threadIdx.x;
    if (bid >= 256){
        const int n = bid - 256;
        float* smf = &xc[0][0];
        float* Ms  = smf;              // 136
        float* Vl  = smf + 144;        // 16*20
        float* Hl2 = smf + 464;        // 16*20
        if (tid < 136) Ms[tid] = ws[OFF_MEAN + n*136 + tid];
        __syncthreads();
        const int t = tid & 15;
        if (tid < 64){
            v2f b[8], v[8]; float nrm = 0.f;
            float* bf = (float*)b;
            float* vf = (float*)v;
#pragma unroll
            for (int i = 0; i < 16; ++i){
                int r = (i > t) ? i : t, c = (i > t) ? t : i;
                bf[i] = Ms[r*(r+1)/2 + c];
                vf[i] = (i == t) ? 1.f : 0.f;
                nrm = fmaf(bf[i], bf[i], nrm);
            }
#pragma unroll 1
            for (int sw = 0; sw < NSWEEP_SMALL; ++sw) jac_sweep<true>(b, v, nrm, t);
            float lam = 0.f;
#pragma unroll
            for (int i = 0; i < 16; ++i) lam = fmaf(vf[i], bf[i], lam);  // signed
            float w = logf(fmaxf(lam, EPSV));
            if (tid < 16){
#pragma unroll
                for (int i = 0; i < 16; ++i){ Vl[i*20 + t] = vf[i]; Hl2[i*20 + t] = w * vf[i]; }
            }
        }
        __syncthreads();
        if (tid < 16){
            for (int k = 0; k < 9; ++k){
                int d = t + 16*k;
                if (d < 136){
                    int r, c; tri_rc(d, r, c);
                    float acc = 0.f;
#pragma unroll
                    for (int j = 0; j < 16; ++j) acc = fmaf(Hl2[r*20 + j], Vl[c*20 + j], acc);
                    float scale = (r == c) ? 1.f : SQRT2F;
                    ws[OFF_XM + n*136 + d] = scale * acc;
                }
            }
        }
        return;
    }
    const int n = bid & 31, c8 = bid >> 5;
    if (tid < 136){
        Gl[tid] = ws[OFF_G + tid];
        Ml[tid] = ws[OFF_MEAN + n*136 + tid];
    }
    int bi = 0, bj = 0; const bool val = (tid < 306);
    if (val){
        int T = tid;
        int bb = (int)floorf((sqrtf(fmaf(4.f, (float)T, 1.f)) - 1.f) * 0.5f);
        while (bb*bb + bb > T) bb--;
        while ((bb+1)*(bb+1) + (bb+1) <= T) bb++;
        bi = bb; bj = T - bb*bb - bb;
    }
    // accumulators as di-pairs: av[p*4+dj] = {a(2p,dj), a(2p+1,dj)}
    v2f av[16];
#pragma unroll
    for (int i = 0; i < 16; ++i) av[i] = (v2f){0.f, 0.f};
    const float* Lbase = ws + OFF_L + (size_t)n * 3200 * 136;
    for (int st = 0; st < 25; ++st){
        __syncthreads();
        int p0 = c8*400 + st*16;
        for (int f = tid; f < 544; f += 512){
            int pp = f / 34, dd = f - pp*34;
            float4 lv = *(const float4*)(Lbase + (size_t)(p0+pp)*136 + dd*4);
            float4 gv = *(const float4*)(&Gl[dd*4]);
            float4 mv = *(const float4*)(&Ml[dd*4]);
            float4 r;
            r.x = (lv.x - mv.x) * gv.x; r.y = (lv.y - mv.y) * gv.y;
            r.z = (lv.z - mv.z) * gv.z; r.w = (lv.w - mv.w) * gv.w;
            *(float4*)(&xc[pp][dd*4]) = r;
        }
        __syncthreads();
        if (val){
#pragma unroll 1
            for (int pp = 0; pp < 16; ++pp){
                const float4 u0 = *(const float4*)(&xc[pp][bi*8]);
                const float4 u1 = *(const float4*)(&xc[pp][bi*8+4]);
                const float4 w4 = *(const float4*)(&xc[pp][bj*4]);
                v2f u01 = {u0.x, u0.y}, u23 = {u0.z, u0.w};
                v2f u45 = {u1.x, u1.y}, u67 = {u1.z, u1.w};
                float wj[4] = {w4.x, w4.y, w4.z, w4.w};
#pragma unroll
                for (int dj = 0; dj < 4; ++dj){
                    v2f wb = {wj[dj], wj[dj]};
                    av[0*4+dj] = pk_fma(u01, wb, av[0*4+dj]);
                    av[1*4+dj] = pk_fma(u23, wb, av[1*4+dj]);
                    av[2*4+dj] = pk_fma(u45, wb, av[2*4+dj]);
                    av[3*4+dj] = pk_fma(u67, wb, av[3*4+dj]);
                }
            }
        }
    }
    if (val){
        float* part = ws + OFF_PART + ((size_t)c8*32 + n)*9316;
#pragma unroll
        for (int p = 0; p < 4; ++p){
#pragma unroll
            for (int h = 0; h < 2; ++h){
                int i = bi*8 + p*2 + h;
#pragma unroll
                for (int dj = 0; dj < 4; ++dj){
                    int j = bj*4 + dj;
                    if (j <= i) part[i*(i+1)/2 + j] = av[p*4+dj][h];
                }
            }
        }
    }
}

// ---------------------------------------------------------------------------
// F: sum partials -> cov (full-matrix LDS, stride 141) -> Cholesky -> write
//    tri-packed factor + trace to ws. Tout/bimap moved to k_tout/k_bimap.
#define TST 141   // T row stride: 141 mod 32 = 13, gcd(13,32)=1 -> conflict-free cols
__global__ __launch_bounds__(512) void k_chol(float* __restrict__ ws){
    __shared__ float T[136*TST];    // 76.7 KB
    __shared__ float ck[136];       // scaled column k (separate object: no aliasing)
    const int n = blockIdx.x;
    const int tid = threadIdx.x;
    // stage cov (tri-packed partials -> full lower)
    for (int e = tid; e < 9316; e += 512){
        float s = 0.f;
#pragma unroll
        for (int c = 0; c < 8; ++c) s += ws[OFF_PART + ((size_t)c*32 + n)*9316 + e];
        int r, cc2; tri_rc(e, r, cc2);
        T[r*TST + cc2] = s * (1.f/3199.f);
    }
    __syncthreads();
    // right-looking Cholesky on lower triangle
    for (int k = 0; k < 136; ++k){
        float d = sqrtf(T[k*TST + k]);
        float rinv = 1.f / d;
        {
            int i = k + 1 + tid;
            if (i < 136){
                float v2 = T[i*TST + k] * rinv;
                T[i*TST + k] = v2;
                ck[i] = v2;
            }
            if (tid == 0) T[k*TST + k] = d;
        }
        __syncthreads();
        const int m = 135 - k;
        const int cnt = m*(m+1)/2;
        const int Lc = (cnt + 511) >> 9;
        int e0 = tid * Lc, e1 = e0 + Lc; if (e1 > cnt) e1 = cnt;
        if (e0 < e1){
            float A = 2.f*m + 1.f;
            int jp = (int)floorf((A - sqrtf(fmaf(A, A, -8.f*e0))) * 0.5f);
            if (jp < 0) jp = 0;
            while (jp > 0 && jp*m - jp*(jp-1)/2 > e0) jp--;
            while ((jp+1)*m - (jp+1)*jp/2 <= e0) jp++;
            int ip = jp + (e0 - (jp*m - jp*(jp-1)/2));
            int i = k+1+ip, j = k+1+jp;
            int ix = i*TST + j;
            int e = e0;
            while (e < e1){
                int nb = e1 - e; if (nb > 8) nb = 8;
                int   ixs[8]; float cis[8], cjs[8], tv[8];
#pragma unroll
                for (int b2 = 0; b2 < 8; ++b2){
                    if (b2 < nb){
                        ixs[b2] = ix; cis[b2] = ck[i]; cjs[b2] = ck[j];
                        i++; ix += TST;
                        if (i == 136){ j++; i = j; ix = i*TST + j; }
                    }
                }
#pragma unroll
                for (int b2 = 0; b2 < 8; ++b2) if (b2 < nb) tv[b2] = T[ixs[b2]];
#pragma unroll
                for (int b2 = 0; b2 < 8; ++b2) if (b2 < nb) tv[b2] = fmaf(-cis[b2], cjs[b2], tv[b2]);
#pragma unroll
                for (int b2 = 0; b2 < 8; ++b2) if (b2 < nb) T[ixs[b2]] = tv[b2];
                e += nb;
            }
        }
        __syncthreads();
    }
    if (tid == 0){
        float tr = 1.f;
        for (int kk = 0; kk < 136; ++kk) tr += T[kk*TST + kk];
        ws[OFF_TR + n*2]     = tr;
        ws[OFF_TR + n*2 + 1] = 1.f / tr;
    }
    // write tri-packed factor (T stable since the k-loop's final barrier)
    for (int e = tid; e < 9316; e += 512){
        int r, c; tri_rc(e, r, c);
        ws[OFF_CT + (size_t)n*9320 + e] = T[r*TST + c];
    }
}

// ---------------------------------------------------------------------------
// F2: Tout rows. 256 blocks: n = bid>>3, s = bid&7 handles rows i = s+8k
//     (k=0..16), s==0 additionally row 136 (xm row). Writes Tt transposed:
//     ws[OFF_TT + n*8960 + q*140 + i].
__global__ __launch_bounds__(512) void k_tout(float* __restrict__ ws){
    __shared__ float Wt[8768];      // [j*64+q]
    __shared__ float tr_[1280];     // staged T rows (flat), max 1224 floats
    __shared__ float xs[137];
    const int bid = blockIdx.x;
    const int n = bid >> 3, s = bid & 7;
    const int tid = threadIdx.x;
    for (int e = tid; e < 8768; e += 512) Wt[e] = ws[OFF_WBT + e];
    const float* ct = ws + OFF_CT + (size_t)n * 9320;
    // stage rows i = s+8k at flat offset off(k) = k*(s+1) + 4k(k-1)
#pragma unroll 1
    for (int k = 0; k < 17; ++k){
        int i = s + 8*k;
        int off = k*(s+1) + 4*k*(k-1);
        int base = i*(i+1)/2;
        for (int e = tid; e <= i; e += 512) tr_[off + e] = ct[base + e];
    }
    if (tid < 137) xs[tid] = (tid < 136) ? ws[OFF_XM + n*136 + tid] : 1.f;
    __syncthreads();
    const float tr  = ws[OFF_TR + n*2];
    const float itr = ws[OFF_TR + n*2 + 1];
    const float c6 = tr * 1e-6f;
    const int q = tid & 63, w = tid >> 6;
    float* tt = ws + OFF_TT + (size_t)n * 8960;
#pragma unroll 1
    for (int k = w; k < 17; k += 8){
        int i = s + 8*k;
        int off = k*(s+1) + 4*k*(k-1);
        float acc = 0.f;
        for (int j = 0; j <= i; ++j) acc = fmaf(tr_[off + j], Wt[j*64 + q], acc);
        tt[q*140 + i] = fmaf(c6, Wt[i*64 + q], itr * acc);
    }
    if (s == 0 && w == 7){          // row 136: [xm | 1] row
        float acc = 0.f;
        for (int j = 0; j < 137; ++j) acc = fmaf(xs[j], Wt[j*64 + q], acc);
        tt[q*140 + 136] = fmaf(c6, Wt[136*64 + q], itr * acc);
    }
}

// ---------------------------------------------------------------------------
// F3: bimap. 256 blocks: n = bid>>3, s = bid&7 computes out rows o = s*8..s*8+7.
//     out[n][o][q] = sum_i Wb[o][i] * Tout[i][q], Tout read transposed (float4).
__global__ __launch_bounds__(512) void k_bimap(const float* __restrict__ ws,
                                               const float* __restrict__ Wb,
                                               float* __restrict__ out){
    __shared__ __align__(16) float Tl[8960];   // TtT: [q*140 + i]
    __shared__ __align__(16) float Wl[1120];   // 8 Wb rows at stride 140
    const int bid = blockIdx.x;
    const int n = bid >> 3, s = bid & 7;
    const int tid = threadIdx.x;
    const float* tt = ws + OFF_TT + (size_t)n * 8960;
    for (int e = tid*4; e < 8960; e += 2048)
        *(float4*)(Tl + e) = *(const float4*)(tt + e);
    for (int e = tid; e < 1096; e += 512){
        int o = e / 137, i = e - o*137;
        Wl[o*140 + i] = Wb[(s*8 + o)*137 + i];
    }
    __syncthreads();
    const int q = tid & 63, ol = tid >> 6;
    const float* tq = Tl + q*140;
    const float* wo = Wl + ol*140;
    float acc = 0.f;
#pragma unroll 1
    for (int i = 0; i < 136; i += 4){
        float4 tv = *(const float4*)(tq + i);
        float4 wv = *(const float4*)(wo + i);
        acc = fmaf(tv.x, wv.x, acc); acc = fmaf(tv.y, wv.y, acc);
        acc = fmaf(tv.z, wv.z, acc); acc = fmaf(tv.w, wv.w, acc);
    }
    acc = fmaf(tq[136], wo[136], acc);
    out[(size_t)n*4096 + (s*8 + ol)*64 + q] = acc;
}

// ---------------------------------------------------------------------------
extern "C" void kernel_launch(void* const* d_in, const int* in_sizes, int n_in,
                              void* d_out, int out_size, void* d_ws, size_t ws_size,
                              hipStream_t stream){
    const float* x   = (const float*)d_in[0];
    const float* W   = (const float*)d_in[1];
    const float* Wb  = (const float*)d_in[2];
    float* out = (float*)d_out;
    float* ws  = (float*)d_ws;

    k_logm   <<<6401, 256, 0, stream>>>(x, ws + OFF_L, ws + OFF_MPART, W, Wb, ws);
    k_xm_mean<<<  32, 256, 0, stream>>>(ws);
    k_cov    <<< 288, 512, 0, stream>>>(ws);
    k_chol   <<<  32, 512, 0, stream>>>(ws);
    k_tout   <<< 256, 512, 0, stream>>>(ws);
    k_bimap  <<< 256, 512, 0, stream>>>(ws, Wb, out);
}

// Round 5
// 730.759 us; speedup vs baseline: 1.2359x; 1.0202x over previous
//
#include <hip/hip_runtime.h>
#include <math.h>

// ---------------------------------------------------------------------------
// RiemannianPooling: logm(eigh) -> mean -> diff_exp -> cov -> cholesky -> bimap
// N=32, M*T*V=3200, C=16, D=136, out 32x64x64 fp32.
// R12: (1) EXACT sweep early-break — a sweep that applies zero rotations
//      leaves b bit-identical, so all later sweeps would vote identical skips;
//      break out (bit-exact). Applies to all three Jacobi call sites.
//      (2) k_logm epilogue: Bl row stride 17->20 (16B-aligned) -> ds_read_b128
//      + genuinely-paired pk_fma for the j-dot (48 b32 -> 12 b128 per k).
//      (3) k_xm_mean: 3-way c-split (408 threads), serial chain 200 -> 67.
//      R11 pk Gram/update kept; R10 pipe-split shuffles kept.
// ---------------------------------------------------------------------------

#define EPSV 1e-4f
#define NSWEEP_BIG 6
#define NSWEEP_SMALL 10
#define SQRT2F 1.41421356237309515f

// workspace layout (float offsets) — total 66.5 MB
#define OFF_G      0            // 136
#define OFF_WBT    160          // 137*64 = 8768
#define OFF_MEAN   8960         // 32*136
#define OFF_XM     13312        // 32*136
#define OFF_TR     17664        // 32*2 (tr, 1/tr)
#define OFF_CT     17792        // 32*9320 tri-packed cholesky factor (ends 316032)
#define OFF_MPART  320000       // 6400*136 (aliases head of PART)
#define OFF_PART   320000       // 8*32*9316 (written after MPART consumed)
#define OFF_TT     320000       // 32*8960 Tout^T (aliases PART, dead after k_chol)
#define OFF_L      2704896      // 102400*136

typedef float v2f __attribute__((ext_vector_type(2)));

__device__ __forceinline__ float rcp_f(float x){ return __builtin_amdgcn_rcpf(x); }
__device__ __forceinline__ float rsq_f(float x){ return __builtin_amdgcn_rsqf(x); }

// Packed fp32 (VOP3P). Only profitable where operands already flow as pairs
// (R11 post-mortem: scalar-consumed halves force v_mov marshaling).
__device__ __forceinline__ v2f pk_fma(v2f a, v2f b, v2f c){
    v2f d;
    asm("v_pk_fma_f32 %0, %1, %2, %3" : "=v"(d) : "v"(a), "v"(b), "v"(c));
    return d;
}
__device__ __forceinline__ v2f pk_mul(v2f a, v2f b){
    v2f d;
    asm("v_pk_mul_f32 %0, %1, %2" : "=v"(d) : "v"(a), "v"(b));
    return d;
}

// XOR within 16-lane rows via single DPP (VALU pipe).
template<int R>
__device__ __forceinline__ float xl(float x){
    int s = __float_as_int(x);
    if constexpr (R == 1){
        return __int_as_float(__builtin_amdgcn_update_dpp(s, s, 0xB1, 0xF, 0xF, false));
    } else if constexpr (R == 2){
        return __int_as_float(__builtin_amdgcn_update_dpp(s, s, 0x4E, 0xF, 0xF, false));
    } else if constexpr (R == 3){
        return __int_as_float(__builtin_amdgcn_update_dpp(s, s, 0x1B, 0xF, 0xF, false));
    } else if constexpr (R == 7){
        return __int_as_float(__builtin_amdgcn_update_dpp(s, s, 0x141, 0xF, 0xF, false));
    } else if constexpr (R == 8){
        return __int_as_float(__builtin_amdgcn_update_dpp(s, s, 0x128, 0xF, 0xF, false));
    } else {  // R == 15
        return __int_as_float(__builtin_amdgcn_update_dpp(s, s, 0x140, 0xF, 0xF, false));
    }
}

// Pipe split: masks {4,5,6,9..14} -> DS crossbar; {1,2,3,7,8,15} on VALU DPP.
// (R9 post-mortem: DO NOT convert the DS ones to 2-DPP compositions — at
// high VALU pressure with multi-wave occupancy the crossbar ops are free, and
// the composition adds ~30% VALU issue -> 375->540us regression.)
template<int R>
__device__ __forceinline__ float shuf(float x){
    if constexpr ((R >= 4 && R <= 6) || R >= 9){
        constexpr int IMM = (R << 10) | 0x1F;   // BitMode: xor=R, and=0x1F
        return __int_as_float(__builtin_amdgcn_ds_swizzle(__float_as_int(x), IMM));
    } else {
        return xl<R>(x);
    }
}

// decode linear lower-tri index d -> (r,c), d = r(r+1)/2 + c
__device__ __forceinline__ void tri_rc(int d, int &r, int &c){
    int rr = (int)floorf((sqrtf(fmaf(8.f, (float)d, 1.f)) - 1.f) * 0.5f);
    if (rr*(rr+1)/2 > d) rr--;
    if ((rr+1)*(rr+2)/2 <= d) rr++;
    r = rr; c = d - rr*(rr+1)/2;
}

// One XOR-tournament round of one-sided Jacobi. 16 lanes per matrix.
// Rotation from (d = nrm-pn, gam) with 2 rsq; per-lane sign automatic
// (d antisymmetric across the pair); wave-uniform noise-floor skip.
// Returns nonzero iff a rotation was applied (wave-uniform).
template<int R, bool WV>
__device__ __forceinline__ int jac_round(v2f* b, v2f* v, float &nrm, int t){
    v2f pc[8];
#pragma unroll
    for (int i = 0; i < 8; ++i){ pc[i].x = shuf<R>(b[i].x); pc[i].y = shuf<R>(b[i].y); }
    float pn = shuf<R>(nrm);
    // Gram dot: 8 pk_fma in 2 chains (4-deep) instead of 16 scalar fma.
    v2f ga = pk_mul(b[0], pc[0]);
    v2f gb = pk_mul(b[1], pc[1]);
    ga = pk_fma(b[2], pc[2], ga); gb = pk_fma(b[3], pc[3], gb);
    ga = pk_fma(b[4], pc[4], ga); gb = pk_fma(b[5], pc[5], gb);
    ga = pk_fma(b[6], pc[6], ga); gb = pk_fma(b[7], pc[7], gb);
    float gam = (ga.x + gb.x) + (ga.y + gb.y);
    // adaptive skip: |gam| <= 4e-7*sqrt(nrm*pn) is update-noise level; if every
    // pair in the wave (4 matrices) is there, the rotations are identity-level.
    bool live = (gam*gam > 1.6e-13f * (nrm * pn));
    int lv = __any((int)live);
    if (lv){
        constexpr int HB = (R & 8) ? 8 : ((R & 4) ? 4 : ((R & 2) ? 2 : 1));
        const bool isp = ((t & HB) == 0);
        // antisymmetric tie-break: if nrm==pn exactly, d still has opposite
        // signs in the two lanes of a pair.
        float d = (nrm - pn) + (isp ? 1e-30f : -1e-30f);
        float g22 = gam + gam;
        float nrr = fmaf(g22, g22, d*d);
        float inv_r = rsq_f(nrr);                      // 1/sqrt(d^2+4g^2)
        float c2 = fmaf(0.5f*fabsf(d), inv_r, 0.5f);   // cos^2(theta), >= 0.5
        float cinv = rsq_f(c2);
        float smag = fabsf(gam) * inv_r * cinv;        // |sin(theta)|
        int sgn = (__float_as_int(gam) ^ __float_as_int(d)) & 0x80000000;
        bool zn = (nrr == 0.f);                        // fully degenerate pair
        float c = zn ? 1.f : c2 * cinv;
        float s = zn ? 0.f : __int_as_float(__float_as_int(smag) | sgn);
        v2f cv = {c, c};
        v2f sv = {s, s};
#pragma unroll
        for (int i = 0; i < 8; ++i) b[i] = pk_fma(pc[i], sv, pk_mul(b[i], cv));
        if (WV){
            v2f pv[8];
#pragma unroll
            for (int i = 0; i < 8; ++i){ pv[i].x = shuf<R>(v[i].x); pv[i].y = shuf<R>(v[i].y); }
#pragma unroll
            for (int i = 0; i < 8; ++i) v[i] = pk_fma(pv[i], sv, pk_mul(v[i], cv));
        }
        nrm = fmaf(s * cinv, gam, nrm);                // alpha' = alpha + t*gam
    }
    return lv;
}

// Returns nonzero iff any round applied a rotation. If zero, b (and v) are
// bit-identical to sweep entry -> all later sweeps are no-ops (exact break).
template<bool WV>
__device__ __forceinline__ int jac_sweep(v2f* b, v2f* v, float &nrm, int t){
    int lv = 0;
    lv |= jac_round< 4,WV>(b,v,nrm,t); lv |= jac_round< 1,WV>(b,v,nrm,t);
    lv |= jac_round< 5,WV>(b,v,nrm,t); lv |= jac_round< 2,WV>(b,v,nrm,t);
    lv |= jac_round< 6,WV>(b,v,nrm,t); lv |= jac_round< 3,WV>(b,v,nrm,t);
    lv |= jac_round< 9,WV>(b,v,nrm,t); lv |= jac_round< 7,WV>(b,v,nrm,t);
    lv |= jac_round<10,WV>(b,v,nrm,t); lv |= jac_round< 8,WV>(b,v,nrm,t);
    lv |= jac_round<11,WV>(b,v,nrm,t); lv |= jac_round<15,WV>(b,v,nrm,t);
    lv |= jac_round<12,WV>(b,v,nrm,t); lv |= jac_round<13,WV>(b,v,nrm,t);
    lv |= jac_round<14,WV>(b,v,nrm,t);
    return lv;
}

// ---------------------------------------------------------------------------
// B: per-matrix eigh + logm lower triangle + per-block mean partials.
__global__ __launch_bounds__(256) void k_logm(const float* __restrict__ x,
                                              float* __restrict__ L,
                                              float* __restrict__ mpart,
                                              const float* __restrict__ W,
                                              const float* __restrict__ Wb,
                                              float* __restrict__ ws){
    __shared__ float sm[5376];     // Bl[16][320] + cof[16][16]  (21.5 KB)
    const int tid = threadIdx.x;
    const int t = tid & 15;
    const int g = tid >> 4;
    if (blockIdx.x == 6400){
        // ---- prep: s = svd(W_sym) desc -> G; WbT transpose ----
        float* sigv  = sm;          // 16
        float* s_srt = sm + 16;     // 16
        if (tid < 64){
            v2f b[8]; float nrm = 0.f;
            float* bf = (float*)b;
#pragma unroll
            for (int i = 0; i < 16; ++i){
                float val = 0.5f * (W[i*16 + t] + W[t*16 + i]);
                bf[i] = val;
                nrm = fmaf(val, val, nrm);
            }
#pragma unroll 1
            for (int sw = 0; sw < NSWEEP_SMALL; ++sw)
                if (!jac_sweep<false>(b, b, nrm, t)) break;
            float n2 = 0.f;
#pragma unroll
            for (int i = 0; i < 16; ++i) n2 = fmaf(bf[i], bf[i], n2);
            float sig = sqrtf(n2);
            if (tid < 16) sigv[t] = sig;
        }
        __syncthreads();
        if (tid < 16){
            float sig = sigv[t];
            int rank = 0;
#pragma unroll
            for (int u = 0; u < 16; ++u){
                float su = sigv[u];
                rank += (su > sig || (su == sig && u < t)) ? 1 : 0;
            }
            s_srt[rank] = sig;   // descending, matches jnp.linalg.svd order
        }
        for (int e = tid; e < 8768; e += 256){
            int o = e / 137, i = e - o*137;
            ws[OFF_WBT + i*64 + o] = Wb[e];
        }
        __syncthreads();
        if (tid < 136){
            int r, c; tri_rc(tid, r, c);
            float sr = s_srt[r], sc = s_srt[c];
            float den = sr - sc;
            bool eq = fabsf(den) < EPSV;
            float er = expf(sr), ec = expf(sc);
            float num = eq ? 0.5f*(er + ec) : (er - ec);
            float dd  = eq ? 1.f : den;
            float scale = (r == c) ? 1.f : SQRT2F;
            ws[OFF_G + tid] = scale * num / dd;
        }
        return;
    }
    float* Bl  = sm;               // g*320 + i*20 + t (16B-aligned rows)
    float* cof = sm + 5120;        // g*16 + j
    const size_t m = (size_t)blockIdx.x * 16 + g;
    const float* xp = x + m * 256;
    v2f b[8]; float nrm = 0.f;
    float* bf = (float*)b;
#pragma unroll
    for (int i = 0; i < 16; ++i){
        float val = xp[i*16 + t];
        bf[i] = val;
        nrm = fmaf(val, val, nrm);
    }
#pragma unroll 1
    for (int sw = 0; sw < NSWEEP_BIG; ++sw)
        if (!jac_sweep<false>(b, b, nrm, t)) break;
    float n2 = 0.f;
#pragma unroll
    for (int i = 0; i < 16; ++i) n2 = fmaf(bf[i], bf[i], n2);
    float lam = sqrtf(n2);
    float w = logf(fmaxf(lam, EPSV));
    float coef = w / n2;            // logm = sum_j coef_j b_j b_j^T
#pragma unroll
    for (int i = 0; i < 16; ++i) Bl[g*320 + i*20 + t] = bf[i];
    cof[g*16 + t] = coef;
    __syncthreads();
    float outv[9];
    float* Lp = L + m * 136;
#pragma unroll
    for (int k = 0; k < 9; ++k){
        int d = t + 16*k;
        float acc = 0.f;
        if (d < 136){
            int r, c; tri_rc(d, r, c);
            const float4* Br = (const float4*)&Bl[g*320 + r*20];
            const float4* Bc = (const float4*)&Bl[g*320 + c*20];
            const float4* Cf = (const float4*)&cof[g*16];
            v2f a2 = {0.f, 0.f};
#pragma unroll
            for (int j4 = 0; j4 < 4; ++j4){
                float4 br = Br[j4], bc = Bc[j4], cf = Cf[j4];
                v2f p1 = pk_mul((v2f){br.x, br.y}, (v2f){cf.x, cf.y});
                a2 = pk_fma(p1, (v2f){bc.x, bc.y}, a2);
                v2f p2 = pk_mul((v2f){br.z, br.w}, (v2f){cf.z, cf.w});
                a2 = pk_fma(p2, (v2f){bc.z, bc.w}, a2);
            }
            acc = a2.x + a2.y;
            Lp[d] = acc;
        }
        outv[k] = acc;
    }
    __syncthreads();
    float* red = sm;                // red[g*144 + d]
#pragma unroll
    for (int k = 0; k < 9; ++k){
        int d = t + 16*k;
        red[g*144 + d] = outv[k];
    }
    __syncthreads();
    if (tid < 136){
        float s = 0.f;
#pragma unroll
        for (int gg = 0; gg < 16; ++gg) s += red[gg*144 + tid];
        mpart[(size_t)blockIdx.x * 136 + tid] = s;
    }
}

// ---------------------------------------------------------------------------
// C: finalize mean from 200 block-partials per n. 3-way c-split (408 threads)
//    cuts the serial load chain 200 -> 67.
__global__ __launch_bounds__(512) void k_xm_mean(float* __restrict__ ws){
    __shared__ float part[3][136];
    const int n = blockIdx.x;
    const int tid = threadIdx.x;
    const int h = tid / 136;
    const int d = tid - h*136;
    if (tid < 408){
        int c0 = h*67, c1 = (h == 2) ? 200 : (c0 + 67);
        const float* mp = ws + OFF_MPART + (size_t)n * 200 * 136 + d;
        float s = 0.f;
#pragma unroll 4
        for (int c = c0; c < c1; ++c) s += mp[(size_t)c * 136];
        part[h][d] = s;
    }
    __syncthreads();
    if (tid < 136)
        ws[OFF_MEAN + n*136 + tid] =
            ((part[0][tid] + part[1][tid]) + part[2][tid]) * (1.f/3200.f);
}

// ---------------------------------------------------------------------------
// E: blocks 0..255: partial covariance. blocks 256..287: xm eigendecomp.
__global__ __launch_bounds__(512) void k_cov(float* __restrict__ ws){
    __shared__ __align__(16) float xc[16][136];
    __shared__ __align__(16) float Gl[136];
    __shared__ __align__(16) float Ml[136];
    const int bid = blockIdx.x;
    const int tid = threadIdx.x;
    if (bid >= 256){
        const int n = bid - 256;
        float* smf = &xc[0][0];
        float* Ms  = smf;              // 136
        float* Vl  = smf + 144;        // 16*20
        float* Hl2 = smf + 464;        // 16*20
        if (tid < 136) Ms[tid] = ws[OFF_MEAN + n*136 + tid];
        __syncthreads();
        const int t = tid & 15;
        if (tid < 64){
            v2f b[8], v[8]; float nrm = 0.f;
            float* bf = (float*)b;
            float* vf = (float*)v;
#pragma unroll
            for (int i = 0; i < 16; ++i){
                int r = (i > t) ? i : t, c = (i > t) ? t : i;
                bf[i] = Ms[r*(r+1)/2 + c];
                vf[i] = (i == t) ? 1.f : 0.f;
                nrm = fmaf(bf[i], bf[i], nrm);
            }
#pragma unroll 1
            for (int sw = 0; sw < NSWEEP_SMALL; ++sw)
                if (!jac_sweep<true>(b, v, nrm, t)) break;
            float lam = 0.f;
#pragma unroll
            for (int i = 0; i < 16; ++i) lam = fmaf(vf[i], bf[i], lam);  // signed
            float w = logf(fmaxf(lam, EPSV));
            if (tid < 16){
#pragma unroll
                for (int i = 0; i < 16; ++i){ Vl[i*20 + t] = vf[i]; Hl2[i*20 + t] = w * vf[i]; }
            }
        }
        __syncthreads();
        if (tid < 16){
            for (int k = 0; k < 9; ++k){
                int d = t + 16*k;
                if (d < 136){
                    int r, c; tri_rc(d, r, c);
                    float acc = 0.f;
#pragma unroll
                    for (int j = 0; j < 16; ++j) acc = fmaf(Hl2[r*20 + j], Vl[c*20 + j], acc);
                    float scale = (r == c) ? 1.f : SQRT2F;
                    ws[OFF_XM + n*136 + d] = scale * acc;
                }
            }
        }
        return;
    }
    const int n = bid & 31, c8 = bid >> 5;
    if (tid < 136){
        Gl[tid] = ws[OFF_G + tid];
        Ml[tid] = ws[OFF_MEAN + n*136 + tid];
    }
    int bi = 0, bj = 0; const bool val = (tid < 306);
    if (val){
        int T = tid;
        int bb = (int)floorf((sqrtf(fmaf(4.f, (float)T, 1.f)) - 1.f) * 0.5f);
        while (bb*bb + bb > T) bb--;
        while ((bb+1)*(bb+1) + (bb+1) <= T) bb++;
        bi = bb; bj = T - bb*bb - bb;
    }
    // accumulators as di-pairs: av[p*4+dj] = {a(2p,dj), a(2p+1,dj)}
    v2f av[16];
#pragma unroll
    for (int i = 0; i < 16; ++i) av[i] = (v2f){0.f, 0.f};
    const float* Lbase = ws + OFF_L + (size_t)n * 3200 * 136;
    for (int st = 0; st < 25; ++st){
        __syncthreads();
        int p0 = c8*400 + st*16;
        for (int f = tid; f < 544; f += 512){
            int pp = f / 34, dd = f - pp*34;
            float4 lv = *(const float4*)(Lbase + (size_t)(p0+pp)*136 + dd*4);
            float4 gv = *(const float4*)(&Gl[dd*4]);
            float4 mv = *(const float4*)(&Ml[dd*4]);
            float4 r;
            r.x = (lv.x - mv.x) * gv.x; r.y = (lv.y - mv.y) * gv.y;
            r.z = (lv.z - mv.z) * gv.z; r.w = (lv.w - mv.w) * gv.w;
            *(float4*)(&xc[pp][dd*4]) = r;
        }
        __syncthreads();
        if (val){
#pragma unroll 1
            for (int pp = 0; pp < 16; ++pp){
                const float4 u0 = *(const float4*)(&xc[pp][bi*8]);
                const float4 u1 = *(const float4*)(&xc[pp][bi*8+4]);
                const float4 w4 = *(const float4*)(&xc[pp][bj*4]);
                v2f u01 = {u0.x, u0.y}, u23 = {u0.z, u0.w};
                v2f u45 = {u1.x, u1.y}, u67 = {u1.z, u1.w};
                float wj[4] = {w4.x, w4.y, w4.z, w4.w};
#pragma unroll
                for (int dj = 0; dj < 4; ++dj){
                    v2f wb = {wj[dj], wj[dj]};
                    av[0*4+dj] = pk_fma(u01, wb, av[0*4+dj]);
                    av[1*4+dj] = pk_fma(u23, wb, av[1*4+dj]);
                    av[2*4+dj] = pk_fma(u45, wb, av[2*4+dj]);
                    av[3*4+dj] = pk_fma(u67, wb, av[3*4+dj]);
                }
            }
        }
    }
    if (val){
        float* part = ws + OFF_PART + ((size_t)c8*32 + n)*9316;
#pragma unroll
        for (int p = 0; p < 4; ++p){
#pragma unroll
            for (int h = 0; h < 2; ++h){
                int i = bi*8 + p*2 + h;
#pragma unroll
                for (int dj = 0; dj < 4; ++dj){
                    int j = bj*4 + dj;
                    if (j <= i) part[i*(i+1)/2 + j] = av[p*4+dj][h];
                }
            }
        }
    }
}

// ---------------------------------------------------------------------------
// F: sum partials -> cov (full-matrix LDS, stride 141) -> Cholesky -> write
//    tri-packed factor + trace to ws. Tout/bimap moved to k_tout/k_bimap.
#define TST 141   // T row stride: 141 mod 32 = 13, gcd(13,32)=1 -> conflict-free cols
__global__ __launch_bounds__(512) void k_chol(float* __restrict__ ws){
    __shared__ float T[136*TST];    // 76.7 KB
    __shared__ float ck[136];       // scaled column k (separate object: no aliasing)
    const int n = blockIdx.x;
    const int tid = threadIdx.x;
    // stage cov (tri-packed partials -> full lower)
    for (int e = tid; e < 9316; e += 512){
        float s = 0.f;
#pragma unroll
        for (int c = 0; c < 8; ++c) s += ws[OFF_PART + ((size_t)c*32 + n)*9316 + e];
        int r, cc2; tri_rc(e, r, cc2);
        T[r*TST + cc2] = s * (1.f/3199.f);
    }
    __syncthreads();
    // right-looking Cholesky on lower triangle
    for (int k = 0; k < 136; ++k){
        float d = sqrtf(T[k*TST + k]);
        float rinv = 1.f / d;
        {
            int i = k + 1 + tid;
            if (i < 136){
                float v2 = T[i*TST + k] * rinv;
                T[i*TST + k] = v2;
                ck[i] = v2;
            }
            if (tid == 0) T[k*TST + k] = d;
        }
        __syncthreads();
        const int m = 135 - k;
        const int cnt = m*(m+1)/2;
        const int Lc = (cnt + 511) >> 9;
        int e0 = tid * Lc, e1 = e0 + Lc; if (e1 > cnt) e1 = cnt;
        if (e0 < e1){
            float A = 2.f*m + 1.f;
            int jp = (int)floorf((A - sqrtf(fmaf(A, A, -8.f*e0))) * 0.5f);
            if (jp < 0) jp = 0;
            while (jp > 0 && jp*m - jp*(jp-1)/2 > e0) jp--;
            while ((jp+1)*m - (jp+1)*jp/2 <= e0) jp++;
            int ip = jp + (e0 - (jp*m - jp*(jp-1)/2));
            int i = k+1+ip, j = k+1+jp;
            int ix = i*TST + j;
            int e = e0;
            while (e < e1){
                int nb = e1 - e; if (nb > 8) nb = 8;
                int   ixs[8]; float cis[8], cjs[8], tv[8];
#pragma unroll
                for (int b2 = 0; b2 < 8; ++b2){
                    if (b2 < nb){
                        ixs[b2] = ix; cis[b2] = ck[i]; cjs[b2] = ck[j];
                        i++; ix += TST;
                        if (i == 136){ j++; i = j; ix = i*TST + j; }
                    }
                }
#pragma unroll
                for (int b2 = 0; b2 < 8; ++b2) if (b2 < nb) tv[b2] = T[ixs[b2]];
#pragma unroll
                for (int b2 = 0; b2 < 8; ++b2) if (b2 < nb) tv[b2] = fmaf(-cis[b2], cjs[b2], tv[b2]);
#pragma unroll
                for (int b2 = 0; b2 < 8; ++b2) if (b2 < nb) T[ixs[b2]] = tv[b2];
                e += nb;
            }
        }
        __syncthreads();
    }
    if (tid == 0){
        float tr = 1.f;
        for (int kk = 0; kk < 136; ++kk) tr += T[kk*TST + kk];
        ws[OFF_TR + n*2]     = tr;
        ws[OFF_TR + n*2 + 1] = 1.f / tr;
    }
    // write tri-packed factor (T stable since the k-loop's final barrier)
    for (int e = tid; e < 9316; e += 512){
        int r, c; tri_rc(e, r, c);
        ws[OFF_CT + (size_t)n*9320 + e] = T[r*TST + c];
    }
}

// ---------------------------------------------------------------------------
// F2: Tout rows. 256 blocks: n = bid>>3, s = bid&7 handles rows i = s+8k
//     (k=0..16), s==0 additionally row 136 (xm row). Writes Tt transposed:
//     ws[OFF_TT + n*8960 + q*140 + i].
__global__ __launch_bounds__(512) void k_tout(float* __restrict__ ws){
    __shared__ float Wt[8768];      // [j*64+q]
    __shared__ float tr_[1280];     // staged T rows (flat), max 1224 floats
    __shared__ float xs[137];
    const int bid = blockIdx.x;
    const int n = bid >> 3, s = bid & 7;
    const int tid = threadIdx.x;
    for (int e = tid; e < 8768; e += 512) Wt[e] = ws[OFF_WBT + e];
    const float* ct = ws + OFF_CT + (size_t)n * 9320;
    // stage rows i = s+8k at flat offset off(k) = k*(s+1) + 4k(k-1)
#pragma unroll 1
    for (int k = 0; k < 17; ++k){
        int i = s + 8*k;
        int off = k*(s+1) + 4*k*(k-1);
        int base = i*(i+1)/2;
        for (int e = tid; e <= i; e += 512) tr_[off + e] = ct[base + e];
    }
    if (tid < 137) xs[tid] = (tid < 136) ? ws[OFF_XM + n*136 + tid] : 1.f;
    __syncthreads();
    const float tr  = ws[OFF_TR + n*2];
    const float itr = ws[OFF_TR + n*2 + 1];
    const float c6 = tr * 1e-6f;
    const int q = tid & 63, w = tid >> 6;
    float* tt = ws + OFF_TT + (size_t)n * 8960;
#pragma unroll 1
    for (int k = w; k < 17; k += 8){
        int i = s + 8*k;
        int off = k*(s+1) + 4*k*(k-1);
        float acc = 0.f;
        for (int j = 0; j <= i; ++j) acc = fmaf(tr_[off + j], Wt[j*64 + q], acc);
        tt[q*140 + i] = fmaf(c6, Wt[i*64 + q], itr * acc);
    }
    if (s == 0 && w == 7){          // row 136: [xm | 1] row
        float acc = 0.f;
        for (int j = 0; j < 137; ++j) acc = fmaf(xs[j], Wt[j*64 + q], acc);
        tt[q*140 + 136] = fmaf(c6, Wt[136*64 + q], itr * acc);
    }
}

// ---------------------------------------------------------------------------
// F3: bimap. 256 blocks: n = bid>>3, s = bid&7 computes out rows o = s*8..s*8+7.
//     out[n][o][q] = sum_i Wb[o][i] * Tout[i][q], Tout read transposed (float4).
__global__ __launch_bounds__(512) void k_bimap(const float* __restrict__ ws,
                                               const float* __restrict__ Wb,
                                               float* __restrict__ out){
    __shared__ __align__(16) float Tl[8960];   // TtT: [q*140 + i]
    __shared__ __align__(16) float Wl[1120];   // 8 Wb rows at stride 140
    const int bid = blockIdx.x;
    const int n = bid >> 3, s = bid & 7;
    const int tid = threadIdx.x;
    const float* tt = ws + OFF_TT + (size_t)n * 8960;
    for (int e = tid*4; e < 8960; e += 2048)
        *(float4*)(Tl + e) = *(const float4*)(tt + e);
    for (int e = tid; e < 1096; e += 512){
        int o = e / 137, i = e - o*137;
        Wl[o*140 + i] = Wb[(s*8 + o)*137 + i];
    }
    __syncthreads();
    const int q = tid & 63, ol = tid >> 6;
    const float* tq = Tl + q*140;
    const float* wo = Wl + ol*140;
    float acc = 0.f;
#pragma unroll 1
    for (int i = 0; i < 136; i += 4){
        float4 tv = *(const float4*)(tq + i);
        float4 wv = *(const float4*)(wo + i);
        acc = fmaf(tv.x, wv.x, acc); acc = fmaf(tv.y, wv.y, acc);
        acc = fmaf(tv.z, wv.z, acc); acc = fmaf(tv.w, wv.w, acc);
    }
    acc = fmaf(tq[136], wo[136], acc);
    out[(size_t)n*4096 + (s*8 + ol)*64 + q] = acc;
}

// ---------------------------------------------------------------------------
extern "C" void kernel_launch(void* const* d_in, const int* in_sizes, int n_in,
                              void* d_out, int out_size, void* d_ws, size_t ws_size,
                              hipStream_t stream){
    const float* x   = (const float*)d_in[0];
    const float* W   = (const float*)d_in[1];
    const float* Wb  = (const float*)d_in[2];
    float* out = (float*)d_out;
    float* ws  = (float*)d_ws;

    k_logm   <<<6401, 256, 0, stream>>>(x, ws + OFF_L, ws + OFF_MPART, W, Wb, ws);
    k_xm_mean<<<  32, 512, 0, stream>>>(ws);
    k_cov    <<< 288, 512, 0, stream>>>(ws);
    k_chol   <<<  32, 512, 0, stream>>>(ws);
    k_tout   <<< 256, 512, 0, stream>>>(ws);
    k_bimap  <<< 256, 512, 0, stream>>>(ws, Wb, out);
}

// Round 6
// 730.444 us; speedup vs baseline: 1.2365x; 1.0004x over previous
//
#include <hip/hip_runtime.h>
#include <math.h>

// ---------------------------------------------------------------------------
// RiemannianPooling: logm(eigh) -> mean -> diff_exp -> cov -> cholesky -> bimap
// N=32, M*T*V=3200, C=16, D=136, out 32x64x64 fp32.
// R13: (1) k_logm LDS 21504 -> 20480 B (cof folded into Bl row padding at
//      i*20+16..19, still float4-readable) -> exactly 8 blocks/CU again
//      (R12 dropped to 7; occupancy 66->59 cost latency hiding).
//      (2) k_cov: 256 cov blocks x 512 thr -> 512 blocks x 256 thr, each
//      computes half the tile-triangle (T = hf*153 + tid) over the same 400
//      samples. Bit-identical partials, disjoint writes; ~2 blocks/CU lets
//      compute of one block cover the stage barrier of the other.
//      R12 break/epilogue/xm_mean kept; R11 pk kept; R10 pipe-split kept.
// ---------------------------------------------------------------------------

#define EPSV 1e-4f
#define NSWEEP_BIG 6
#define NSWEEP_SMALL 10
#define SQRT2F 1.41421356237309515f

// workspace layout (float offsets) — total 66.5 MB
#define OFF_G      0            // 136
#define OFF_WBT    160          // 137*64 = 8768
#define OFF_MEAN   8960         // 32*136
#define OFF_XM     13312        // 32*136
#define OFF_TR     17664        // 32*2 (tr, 1/tr)
#define OFF_CT     17792        // 32*9320 tri-packed cholesky factor (ends 316032)
#define OFF_MPART  320000       // 6400*136 (aliases head of PART)
#define OFF_PART   320000       // 8*32*9316 (written after MPART consumed)
#define OFF_TT     320000       // 32*8960 Tout^T (aliases PART, dead after k_chol)
#define OFF_L      2704896      // 102400*136

typedef float v2f __attribute__((ext_vector_type(2)));

__device__ __forceinline__ float rcp_f(float x){ return __builtin_amdgcn_rcpf(x); }
__device__ __forceinline__ float rsq_f(float x){ return __builtin_amdgcn_rsqf(x); }

// Packed fp32 (VOP3P). Only profitable where operands already flow as pairs
// (R11 post-mortem: scalar-consumed halves force v_mov marshaling).
__device__ __forceinline__ v2f pk_fma(v2f a, v2f b, v2f c){
    v2f d;
    asm("v_pk_fma_f32 %0, %1, %2, %3" : "=v"(d) : "v"(a), "v"(b), "v"(c));
    return d;
}
__device__ __forceinline__ v2f pk_mul(v2f a, v2f b){
    v2f d;
    asm("v_pk_mul_f32 %0, %1, %2" : "=v"(d) : "v"(a), "v"(b));
    return d;
}

// XOR within 16-lane rows via single DPP (VALU pipe).
template<int R>
__device__ __forceinline__ float xl(float x){
    int s = __float_as_int(x);
    if constexpr (R == 1){
        return __int_as_float(__builtin_amdgcn_update_dpp(s, s, 0xB1, 0xF, 0xF, false));
    } else if constexpr (R == 2){
        return __int_as_float(__builtin_amdgcn_update_dpp(s, s, 0x4E, 0xF, 0xF, false));
    } else if constexpr (R == 3){
        return __int_as_float(__builtin_amdgcn_update_dpp(s, s, 0x1B, 0xF, 0xF, false));
    } else if constexpr (R == 7){
        return __int_as_float(__builtin_amdgcn_update_dpp(s, s, 0x141, 0xF, 0xF, false));
    } else if constexpr (R == 8){
        return __int_as_float(__builtin_amdgcn_update_dpp(s, s, 0x128, 0xF, 0xF, false));
    } else {  // R == 15
        return __int_as_float(__builtin_amdgcn_update_dpp(s, s, 0x140, 0xF, 0xF, false));
    }
}

// Pipe split: masks {4,5,6,9..14} -> DS crossbar; {1,2,3,7,8,15} on VALU DPP.
// (R9 post-mortem: DO NOT convert the DS ones to 2-DPP compositions — at
// high VALU pressure with multi-wave occupancy the crossbar ops are free, and
// the composition adds ~30% VALU issue -> 375->540us regression.)
template<int R>
__device__ __forceinline__ float shuf(float x){
    if constexpr ((R >= 4 && R <= 6) || R >= 9){
        constexpr int IMM = (R << 10) | 0x1F;   // BitMode: xor=R, and=0x1F
        return __int_as_float(__builtin_amdgcn_ds_swizzle(__float_as_int(x), IMM));
    } else {
        return xl<R>(x);
    }
}

// decode linear lower-tri index d -> (r,c), d = r(r+1)/2 + c
__device__ __forceinline__ void tri_rc(int d, int &r, int &c){
    int rr = (int)floorf((sqrtf(fmaf(8.f, (float)d, 1.f)) - 1.f) * 0.5f);
    if (rr*(rr+1)/2 > d) rr--;
    if ((rr+1)*(rr+2)/2 <= d) rr++;
    r = rr; c = d - rr*(rr+1)/2;
}

// One XOR-tournament round of one-sided Jacobi. 16 lanes per matrix.
// Rotation from (d = nrm-pn, gam) with 2 rsq; per-lane sign automatic
// (d antisymmetric across the pair); wave-uniform noise-floor skip.
// Returns nonzero iff a rotation was applied (wave-uniform).
template<int R, bool WV>
__device__ __forceinline__ int jac_round(v2f* b, v2f* v, float &nrm, int t){
    v2f pc[8];
#pragma unroll
    for (int i = 0; i < 8; ++i){ pc[i].x = shuf<R>(b[i].x); pc[i].y = shuf<R>(b[i].y); }
    float pn = shuf<R>(nrm);
    // Gram dot: 8 pk_fma in 2 chains (4-deep) instead of 16 scalar fma.
    v2f ga = pk_mul(b[0], pc[0]);
    v2f gb = pk_mul(b[1], pc[1]);
    ga = pk_fma(b[2], pc[2], ga); gb = pk_fma(b[3], pc[3], gb);
    ga = pk_fma(b[4], pc[4], ga); gb = pk_fma(b[5], pc[5], gb);
    ga = pk_fma(b[6], pc[6], ga); gb = pk_fma(b[7], pc[7], gb);
    float gam = (ga.x + gb.x) + (ga.y + gb.y);
    // adaptive skip: |gam| <= 4e-7*sqrt(nrm*pn) is update-noise level; if every
    // pair in the wave (4 matrices) is there, the rotations are identity-level.
    bool live = (gam*gam > 1.6e-13f * (nrm * pn));
    int lv = __any((int)live);
    if (lv){
        constexpr int HB = (R & 8) ? 8 : ((R & 4) ? 4 : ((R & 2) ? 2 : 1));
        const bool isp = ((t & HB) == 0);
        // antisymmetric tie-break: if nrm==pn exactly, d still has opposite
        // signs in the two lanes of a pair.
        float d = (nrm - pn) + (isp ? 1e-30f : -1e-30f);
        float g22 = gam + gam;
        float nrr = fmaf(g22, g22, d*d);
        float inv_r = rsq_f(nrr);                      // 1/sqrt(d^2+4g^2)
        float c2 = fmaf(0.5f*fabsf(d), inv_r, 0.5f);   // cos^2(theta), >= 0.5
        float cinv = rsq_f(c2);
        float smag = fabsf(gam) * inv_r * cinv;        // |sin(theta)|
        int sgn = (__float_as_int(gam) ^ __float_as_int(d)) & 0x80000000;
        bool zn = (nrr == 0.f);                        // fully degenerate pair
        float c = zn ? 1.f : c2 * cinv;
        float s = zn ? 0.f : __int_as_float(__float_as_int(smag) | sgn);
        v2f cv = {c, c};
        v2f sv = {s, s};
#pragma unroll
        for (int i = 0; i < 8; ++i) b[i] = pk_fma(pc[i], sv, pk_mul(b[i], cv));
        if (WV){
            v2f pv[8];
#pragma unroll
            for (int i = 0; i < 8; ++i){ pv[i].x = shuf<R>(v[i].x); pv[i].y = shuf<R>(v[i].y); }
#pragma unroll
            for (int i = 0; i < 8; ++i) v[i] = pk_fma(pv[i], sv, pk_mul(v[i], cv));
        }
        nrm = fmaf(s * cinv, gam, nrm);                // alpha' = alpha + t*gam
    }
    return lv;
}

// Returns nonzero iff any round applied a rotation. If zero, b (and v) are
// bit-identical to sweep entry -> all later sweeps are no-ops (exact break).
template<bool WV>
__device__ __forceinline__ int jac_sweep(v2f* b, v2f* v, float &nrm, int t){
    int lv = 0;
    lv |= jac_round< 4,WV>(b,v,nrm,t); lv |= jac_round< 1,WV>(b,v,nrm,t);
    lv |= jac_round< 5,WV>(b,v,nrm,t); lv |= jac_round< 2,WV>(b,v,nrm,t);
    lv |= jac_round< 6,WV>(b,v,nrm,t); lv |= jac_round< 3,WV>(b,v,nrm,t);
    lv |= jac_round< 9,WV>(b,v,nrm,t); lv |= jac_round< 7,WV>(b,v,nrm,t);
    lv |= jac_round<10,WV>(b,v,nrm,t); lv |= jac_round< 8,WV>(b,v,nrm,t);
    lv |= jac_round<11,WV>(b,v,nrm,t); lv |= jac_round<15,WV>(b,v,nrm,t);
    lv |= jac_round<12,WV>(b,v,nrm,t); lv |= jac_round<13,WV>(b,v,nrm,t);
    lv |= jac_round<14,WV>(b,v,nrm,t);
    return lv;
}

// ---------------------------------------------------------------------------
// B: per-matrix eigh + logm lower triangle + per-block mean partials.
__global__ __launch_bounds__(256) void k_logm(const float* __restrict__ x,
                                              float* __restrict__ L,
                                              float* __restrict__ mpart,
                                              const float* __restrict__ W,
                                              const float* __restrict__ Wb,
                                              float* __restrict__ ws){
    __shared__ float sm[5120];     // Bl[16][16 rows x 20] with cof in padding
                                   // (20480 B = exactly 160KB/8 -> 8 blocks/CU)
    const int tid = threadIdx.x;
    const int t = tid & 15;
    const int g = tid >> 4;
    if (blockIdx.x == 6400){
        // ---- prep: s = svd(W_sym) desc -> G; WbT transpose ----
        float* sigv  = sm;          // 16
        float* s_srt = sm + 16;     // 16
        if (tid < 64){
            v2f b[8]; float nrm = 0.f;
            float* bf = (float*)b;
#pragma unroll
            for (int i = 0; i < 16; ++i){
                float val = 0.5f * (W[i*16 + t] + W[t*16 + i]);
                bf[i] = val;
                nrm = fmaf(val, val, nrm);
            }
#pragma unroll 1
            for (int sw = 0; sw < NSWEEP_SMALL; ++sw)
                if (!jac_sweep<false>(b, b, nrm, t)) break;
            float n2 = 0.f;
#pragma unroll
            for (int i = 0; i < 16; ++i) n2 = fmaf(bf[i], bf[i], n2);
            float sig = sqrtf(n2);
            if (tid < 16) sigv[t] = sig;
        }
        __syncthreads();
        if (tid < 16){
            float sig = sigv[t];
            int rank = 0;
#pragma unroll
            for (int u = 0; u < 16; ++u){
                float su = sigv[u];
                rank += (su > sig || (su == sig && u < t)) ? 1 : 0;
            }
            s_srt[rank] = sig;   // descending, matches jnp.linalg.svd order
        }
        for (int e = tid; e < 8768; e += 256){
            int o = e / 137, i = e - o*137;
            ws[OFF_WBT + i*64 + o] = Wb[e];
        }
        __syncthreads();
        if (tid < 136){
            int r, c; tri_rc(tid, r, c);
            float sr = s_srt[r], sc = s_srt[c];
            float den = sr - sc;
            bool eq = fabsf(den) < EPSV;
            float er = expf(sr), ec = expf(sc);
            float num = eq ? 0.5f*(er + ec) : (er - ec);
            float dd  = eq ? 1.f : den;
            float scale = (r == c) ? 1.f : SQRT2F;
            ws[OFF_G + tid] = scale * num / dd;
        }
        return;
    }
    float* Bl = sm;                // g*320 + i*20 + t; cof[j] at g*320+(j>>2)*20+16+(j&3)
    const size_t m = (size_t)blockIdx.x * 16 + g;
    const float* xp = x + m * 256;
    v2f b[8]; float nrm = 0.f;
    float* bf = (float*)b;
#pragma unroll
    for (int i = 0; i < 16; ++i){
        float val = xp[i*16 + t];
        bf[i] = val;
        nrm = fmaf(val, val, nrm);
    }
#pragma unroll 1
    for (int sw = 0; sw < NSWEEP_BIG; ++sw)
        if (!jac_sweep<false>(b, b, nrm, t)) break;
    float n2 = 0.f;
#pragma unroll
    for (int i = 0; i < 16; ++i) n2 = fmaf(bf[i], bf[i], n2);
    float lam = sqrtf(n2);
    float w = logf(fmaxf(lam, EPSV));
    float coef = w / n2;            // logm = sum_j coef_j b_j b_j^T
#pragma unroll
    for (int i = 0; i < 16; ++i) Bl[g*320 + i*20 + t] = bf[i];
    Bl[g*320 + (t>>2)*20 + 16 + (t&3)] = coef;   // cof[t] in row-t>>2 padding
    __syncthreads();
    float outv[9];
    float* Lp = L + m * 136;
#pragma unroll
    for (int k = 0; k < 9; ++k){
        int d = t + 16*k;
        float acc = 0.f;
        if (d < 136){
            int r, c; tri_rc(d, r, c);
            const float4* Br = (const float4*)&Bl[g*320 + r*20];
            const float4* Bc = (const float4*)&Bl[g*320 + c*20];
            v2f a2 = {0.f, 0.f};
#pragma unroll
            for (int j4 = 0; j4 < 4; ++j4){
                float4 br = Br[j4], bc = Bc[j4];
                float4 cf = *(const float4*)&Bl[g*320 + j4*20 + 16];
                v2f p1 = pk_mul((v2f){br.x, br.y}, (v2f){cf.x, cf.y});
                a2 = pk_fma(p1, (v2f){bc.x, bc.y}, a2);
                v2f p2 = pk_mul((v2f){br.z, br.w}, (v2f){cf.z, cf.w});
                a2 = pk_fma(p2, (v2f){bc.z, bc.w}, a2);
            }
            acc = a2.x + a2.y;
            Lp[d] = acc;
        }
        outv[k] = acc;
    }
    __syncthreads();
    float* red = sm;                // red[g*144 + d]
#pragma unroll
    for (int k = 0; k < 9; ++k){
        int d = t + 16*k;
        red[g*144 + d] = outv[k];
    }
    __syncthreads();
    if (tid < 136){
        float s = 0.f;
#pragma unroll
        for (int gg = 0; gg < 16; ++gg) s += red[gg*144 + tid];
        mpart[(size_t)blockIdx.x * 136 + tid] = s;
    }
}

// ---------------------------------------------------------------------------
// C: finalize mean from 200 block-partials per n. 3-way c-split (408 threads)
//    cuts the serial load chain 200 -> 67.
__global__ __launch_bounds__(512) void k_xm_mean(float* __restrict__ ws){
    __shared__ float part[3][136];
    const int n = blockIdx.x;
    const int tid = threadIdx.x;
    const int h = tid / 136;
    const int d = tid - h*136;
    if (tid < 408){
        int c0 = h*67, c1 = (h == 2) ? 200 : (c0 + 67);
        const float* mp = ws + OFF_MPART + (size_t)n * 200 * 136 + d;
        float s = 0.f;
#pragma unroll 4
        for (int c = c0; c < c1; ++c) s += mp[(size_t)c * 136];
        part[h][d] = s;
    }
    __syncthreads();
    if (tid < 136)
        ws[OFF_MEAN + n*136 + tid] =
            ((part[0][tid] + part[1][tid]) + part[2][tid]) * (1.f/3200.f);
}

// ---------------------------------------------------------------------------
// E: blocks 0..511: partial covariance, block (n, c8, hf) computes tile-
//    triangle half T = hf*153 + tid over stages of its c8 group (bit-identical
//    per-element accumulation vs the 512-thread version; disjoint writes).
//    Blocks 512..543: xm eigendecomp.
__global__ __launch_bounds__(256) void k_cov(float* __restrict__ ws){
    __shared__ __align__(16) float xc[16][136];
    __shared__ __align__(16) float Gl[136];
    __shared__ __align__(16) float Ml[136];
    const int bid = blockIdx.x;
    const int tid = threadIdx.x;
    if (bid >= 512){
        const int n = bid - 512;
        float* smf = &xc[0][0];
        float* Ms  = smf;              // 136
        float* Vl  = smf + 144;        // 16*20
        float* Hl2 = smf + 464;        // 16*20
        if (tid < 136) Ms[tid] = ws[OFF_MEAN + n*136 + tid];
        __syncthreads();
        const int t = tid & 15;
        if (tid < 64){
            v2f b[8], v[8]; float nrm = 0.f;
            float* bf = (float*)b;
            float* vf = (float*)v;
#pragma unroll
            for (int i = 0; i < 16; ++i){
                int r = (i > t) ? i : t, c = (i > t) ? t : i;
                bf[i] = Ms[r*(r+1)/2 + c];
                vf[i] = (i == t) ? 1.f : 0.f;
                nrm = fmaf(bf[i], bf[i], nrm);
            }
#pragma unroll 1
            for (int sw = 0; sw < NSWEEP_SMALL; ++sw)
                if (!jac_sweep<true>(b, v, nrm, t)) break;
            float lam = 0.f;
#pragma unroll
            for (int i = 0; i < 16; ++i) lam = fmaf(vf[i], bf[i], lam);  // signed
            float w = logf(fmaxf(lam, EPSV));
            if (tid < 16){
#pragma unroll
                for (int i = 0; i < 16; ++i){ Vl[i*20 + t] = vf[i]; Hl2[i*20 + t] = w * vf[i]; }
            }
        }
        __syncthreads();
        if (tid < 16){
            for (int k = 0; k < 9; ++k){
                int d = t + 16*k;
                if (d < 136){
                    int r, c; tri_rc(d, r, c);
                    float acc = 0.f;
#pragma unroll
                    for (int j = 0; j < 16; ++j) acc = fmaf(Hl2[r*20 + j], Vl[c*20 + j], acc);
                    float scale = (r == c) ? 1.f : SQRT2F;
                    ws[OFF_XM + n*136 + d] = scale * acc;
                }
            }
        }
        return;
    }
    const int n = bid & 31, c8 = (bid >> 5) & 7, hf = bid >> 8;
    if (tid < 136){
        Gl[tid] = ws[OFF_G + tid];
        Ml[tid] = ws[OFF_MEAN + n*136 + tid];
    }
    int bi = 0, bj = 0; const bool val = (tid < 153);
    if (val){
        int T = hf*153 + tid;
        int bb = (int)floorf((sqrtf(fmaf(4.f, (float)T, 1.f)) - 1.f) * 0.5f);
        while (bb*bb + bb > T) bb--;
        while ((bb+1)*(bb+1) + (bb+1) <= T) bb++;
        bi = bb; bj = T - bb*bb - bb;
    }
    // accumulators as di-pairs: av[p*4+dj] = {a(2p,dj), a(2p+1,dj)}
    v2f av[16];
#pragma unroll
    for (int i = 0; i < 16; ++i) av[i] = (v2f){0.f, 0.f};
    const float* Lbase = ws + OFF_L + (size_t)n * 3200 * 136;
    for (int st = 0; st < 25; ++st){
        __syncthreads();
        int p0 = c8*400 + st*16;
        for (int f = tid; f < 544; f += 256){
            int pp = f / 34, dd = f - pp*34;
            float4 lv = *(const float4*)(Lbase + (size_t)(p0+pp)*136 + dd*4);
            float4 gv = *(const float4*)(&Gl[dd*4]);
            float4 mv = *(const float4*)(&Ml[dd*4]);
            float4 r;
            r.x = (lv.x - mv.x) * gv.x; r.y = (lv.y - mv.y) * gv.y;
            r.z = (lv.z - mv.z) * gv.z; r.w = (lv.w - mv.w) * gv.w;
            *(float4*)(&xc[pp][dd*4]) = r;
        }
        __syncthreads();
        if (val){
#pragma unroll 1
            for (int pp = 0; pp < 16; ++pp){
                const float4 u0 = *(const float4*)(&xc[pp][bi*8]);
                const float4 u1 = *(const float4*)(&xc[pp][bi*8+4]);
                const float4 w4 = *(const float4*)(&xc[pp][bj*4]);
                v2f u01 = {u0.x, u0.y}, u23 = {u0.z, u0.w};
                v2f u45 = {u1.x, u1.y}, u67 = {u1.z, u1.w};
                float wj[4] = {w4.x, w4.y, w4.z, w4.w};
#pragma unroll
                for (int dj = 0; dj < 4; ++dj){
                    v2f wb = {wj[dj], wj[dj]};
                    av[0*4+dj] = pk_fma(u01, wb, av[0*4+dj]);
                    av[1*4+dj] = pk_fma(u23, wb, av[1*4+dj]);
                    av[2*4+dj] = pk_fma(u45, wb, av[2*4+dj]);
                    av[3*4+dj] = pk_fma(u67, wb, av[3*4+dj]);
                }
            }
        }
    }
    if (val){
        float* part = ws + OFF_PART + ((size_t)c8*32 + n)*9316;
#pragma unroll
        for (int p = 0; p < 4; ++p){
#pragma unroll
            for (int h = 0; h < 2; ++h){
                int i = bi*8 + p*2 + h;
#pragma unroll
                for (int dj = 0; dj < 4; ++dj){
                    int j = bj*4 + dj;
                    if (j <= i) part[i*(i+1)/2 + j] = av[p*4+dj][h];
                }
            }
        }
    }
}

// ---------------------------------------------------------------------------
// F: sum partials -> cov (full-matrix LDS, stride 141) -> Cholesky -> write
//    tri-packed factor + trace to ws. Tout/bimap moved to k_tout/k_bimap.
#define TST 141   // T row stride: 141 mod 32 = 13, gcd(13,32)=1 -> conflict-free cols
__global__ __launch_bounds__(512) void k_chol(float* __restrict__ ws){
    __shared__ float T[136*TST];    // 76.7 KB
    __shared__ float ck[136];       // scaled column k (separate object: no aliasing)
    const int n = blockIdx.x;
    const int tid = threadIdx.x;
    // stage cov (tri-packed partials -> full lower)
    for (int e = tid; e < 9316; e += 512){
        float s = 0.f;
#pragma unroll
        for (int c = 0; c < 8; ++c) s += ws[OFF_PART + ((size_t)c*32 + n)*9316 + e];
        int r, cc2; tri_rc(e, r, cc2);
        T[r*TST + cc2] = s * (1.f/3199.f);
    }
    __syncthreads();
    // right-looking Cholesky on lower triangle
    for (int k = 0; k < 136; ++k){
        float d = sqrtf(T[k*TST + k]);
        float rinv = 1.f / d;
        {
            int i = k + 1 + tid;
            if (i < 136){
                float v2 = T[i*TST + k] * rinv;
                T[i*TST + k] = v2;
                ck[i] = v2;
            }
            if (tid == 0) T[k*TST + k] = d;
        }
        __syncthreads();
        const int m = 135 - k;
        const int cnt = m*(m+1)/2;
        const int Lc = (cnt + 511) >> 9;
        int e0 = tid * Lc, e1 = e0 + Lc; if (e1 > cnt) e1 = cnt;
        if (e0 < e1){
            float A = 2.f*m + 1.f;
            int jp = (int)floorf((A - sqrtf(fmaf(A, A, -8.f*e0))) * 0.5f);
            if (jp < 0) jp = 0;
            while (jp > 0 && jp*m - jp*(jp-1)/2 > e0) jp--;
            while ((jp+1)*m - (jp+1)*jp/2 <= e0) jp++;
            int ip = jp + (e0 - (jp*m - jp*(jp-1)/2));
            int i = k+1+ip, j = k+1+jp;
            int ix = i*TST + j;
            int e = e0;
            while (e < e1){
                int nb = e1 - e; if (nb > 8) nb = 8;
                int   ixs[8]; float cis[8], cjs[8], tv[8];
#pragma unroll
                for (int b2 = 0; b2 < 8; ++b2){
                    if (b2 < nb){
                        ixs[b2] = ix; cis[b2] = ck[i]; cjs[b2] = ck[j];
                        i++; ix += TST;
                        if (i == 136){ j++; i = j; ix = i*TST + j; }
                    }
                }
#pragma unroll
                for (int b2 = 0; b2 < 8; ++b2) if (b2 < nb) tv[b2] = T[ixs[b2]];
#pragma unroll
                for (int b2 = 0; b2 < 8; ++b2) if (b2 < nb) tv[b2] = fmaf(-cis[b2], cjs[b2], tv[b2]);
#pragma unroll
                for (int b2 = 0; b2 < 8; ++b2) if (b2 < nb) T[ixs[b2]] = tv[b2];
                e += nb;
            }
        }
        __syncthreads();
    }
    if (tid == 0){
        float tr = 1.f;
        for (int kk = 0; kk < 136; ++kk) tr += T[kk*TST + kk];
        ws[OFF_TR + n*2]     = tr;
        ws[OFF_TR + n*2 + 1] = 1.f / tr;
    }
    // write tri-packed factor (T stable since the k-loop's final barrier)
    for (int e = tid; e < 9316; e += 512){
        int r, c; tri_rc(e, r, c);
        ws[OFF_CT + (size_t)n*9320 + e] = T[r*TST + c];
    }
}

// ---------------------------------------------------------------------------
// F2: Tout rows. 256 blocks: n = bid>>3, s = bid&7 handles rows i = s+8k
//     (k=0..16), s==0 additionally row 136 (xm row). Writes Tt transposed:
//     ws[OFF_TT + n*8960 + q*140 + i].
__global__ __launch_bounds__(512) void k_tout(float* __restrict__ ws){
    __shared__ float Wt[8768];      // [j*64+q]
    __shared__ float tr_[1280];     // staged T rows (flat), max 1224 floats
    __shared__ float xs[137];
    const int bid = blockIdx.x;
    const int n = bid >> 3, s = bid & 7;
    const int tid = threadIdx.x;
    for (int e = tid; e < 8768; e += 512) Wt[e] = ws[OFF_WBT + e];
    const float* ct = ws + OFF_CT + (size_t)n * 9320;
    // stage rows i = s+8k at flat offset off(k) = k*(s+1) + 4k(k-1)
#pragma unroll 1
    for (int k = 0; k < 17; ++k){
        int i = s + 8*k;
        int off = k*(s+1) + 4*k*(k-1);
        int base = i*(i+1)/2;
        for (int e = tid; e <= i; e += 512) tr_[off + e] = ct[base + e];
    }
    if (tid < 137) xs[tid] = (tid < 136) ? ws[OFF_XM + n*136 + tid] : 1.f;
    __syncthreads();
    const float tr  = ws[OFF_TR + n*2];
    const float itr = ws[OFF_TR + n*2 + 1];
    const float c6 = tr * 1e-6f;
    const int q = tid & 63, w = tid >> 6;
    float* tt = ws + OFF_TT + (size_t)n * 8960;
#pragma unroll 1
    for (int k = w; k < 17; k += 8){
        int i = s + 8*k;
        int off = k*(s+1) + 4*k*(k-1);
        float acc = 0.f;
        for (int j = 0; j <= i; ++j) acc = fmaf(tr_[off + j], Wt[j*64 + q], acc);
        tt[q*140 + i] = fmaf(c6, Wt[i*64 + q], itr * acc);
    }
    if (s == 0 && w == 7){          // row 136: [xm | 1] row
        float acc = 0.f;
        for (int j = 0; j < 137; ++j) acc = fmaf(xs[j], Wt[j*64 + q], acc);
        tt[q*140 + 136] = fmaf(c6, Wt[136*64 + q], itr * acc);
    }
}

// ---------------------------------------------------------------------------
// F3: bimap. 256 blocks: n = bid>>3, s = bid&7 computes out rows o = s*8..s*8+7.
//     out[n][o][q] = sum_i Wb[o][i] * Tout[i][q], Tout read transposed (float4).
__global__ __launch_bounds__(512) void k_bimap(const float* __restrict__ ws,
                                               const float* __restrict__ Wb,
                                               float* __restrict__ out){
    __shared__ __align__(16) float Tl[8960];   // TtT: [q*140 + i]
    __shared__ __align__(16) float Wl[1120];   // 8 Wb rows at stride 140
    const int bid = blockIdx.x;
    const int n = bid >> 3, s = bid & 7;
    const int tid = threadIdx.x;
    const float* tt = ws + OFF_TT + (size_t)n * 8960;
    for (int e = tid*4; e < 8960; e += 2048)
        *(float4*)(Tl + e) = *(const float4*)(tt + e);
    for (int e = tid; e < 1096; e += 512){
        int o = e / 137, i = e - o*137;
        Wl[o*140 + i] = Wb[(s*8 + o)*137 + i];
    }
    __syncthreads();
    const int q = tid & 63, ol = tid >> 6;
    const float* tq = Tl + q*140;
    const float* wo = Wl + ol*140;
    float acc = 0.f;
#pragma unroll 1
    for (int i = 0; i < 136; i += 4){
        float4 tv = *(const float4*)(tq + i);
        float4 wv = *(const float4*)(wo + i);
        acc = fmaf(tv.x, wv.x, acc); acc = fmaf(tv.y, wv.y, acc);
        acc = fmaf(tv.z, wv.z, acc); acc = fmaf(tv.w, wv.w, acc);
    }
    acc = fmaf(tq[136], wo[136], acc);
    out[(size_t)n*4096 + (s*8 + ol)*64 + q] = acc;
}

// ---------------------------------------------------------------------------
extern "C" void kernel_launch(void* const* d_in, const int* in_sizes, int n_in,
                              void* d_out, int out_size, void* d_ws, size_t ws_size,
                              hipStream_t stream){
    const float* x   = (const float*)d_in[0];
    const float* W   = (const float*)d_in[1];
    const float* Wb  = (const float*)d_in[2];
    float* out = (float*)d_out;
    float* ws  = (float*)d_ws;

    k_logm   <<<6401, 256, 0, stream>>>(x, ws + OFF_L, ws + OFF_MPART, W, Wb, ws);
    k_xm_mean<<<  32, 512, 0, stream>>>(ws);
    k_cov    <<< 544, 256, 0, stream>>>(ws);
    k_chol   <<<  32, 512, 0, stream>>>(ws);
    k_tout   <<< 256, 512, 0, stream>>>(ws);
    k_bimap  <<< 256, 512, 0, stream>>>(ws, Wb, out);
}